// Round 1
// baseline (34937.955 us; speedup 1.0000x reference)
//
#include <hip/hip_runtime.h>
#include <hip/hip_cooperative_groups.h>

namespace cg = cooperative_groups;

typedef _Float16 f16;
typedef _Float16 f16x8 __attribute__((ext_vector_type(8)));
typedef float f32x4 __attribute__((ext_vector_type(4)));

#define NB 32
#define NT 256
#define NE 256
#define NU 1024
#define NV 128

// ---------------- embedding: seq0[t*NB+b][e] = emb[x[b][t]][e] (f16) ----------------
__global__ void embed_kernel(const int* __restrict__ x, const float* __restrict__ emb,
                             f16* __restrict__ seq0) {
    int row = blockIdx.x;           // t*NB + b
    int t = row >> 5, b = row & 31;
    int e = threadIdx.x;            // 256 threads == NE
    int idx = x[b * NT + t];
    seq0[row * NE + e] = (f16)emb[idx * NE + e];
}

// ---------------- input-projection GEMM: proj[row][0:2048]=x@Wg_x+bg, [2048:3072]=x@Wc_x+bc ----
// A: [8192, K] f16 (pitch lda). grid (64, 24). 256 threads, 4 waves, 128x128 tile, BK=32.
__launch_bounds__(256)
__global__ void gemm_proj(const f16* __restrict__ A, int lda, int K,
                          const float* __restrict__ Wg, const float* __restrict__ Wc,
                          const float* __restrict__ bg, const float* __restrict__ bc,
                          f16* __restrict__ proj) {
    __shared__ f16 As[128][40];
    __shared__ f16 Bs[128][40];
    int cb = blockIdx.y;
    const float* Bsrc; int ldb, outcol; const float* bias;
    if (cb < 16) { Bsrc = Wg + cb * 128; ldb = 2 * NU; outcol = cb * 128; bias = bg + cb * 128; }
    else { Bsrc = Wc + (cb - 16) * 128; ldb = NU; outcol = 2 * NU + (cb - 16) * 128; bias = bc + (cb - 16) * 128; }
    int m0 = blockIdx.x * 128;
    int tid = threadIdx.x;
    int w = tid >> 6, l = tid & 63;
    int wm = w & 1, wn = w >> 1;
    f32x4 acc[4][4] = {};
    for (int k0 = 0; k0 < K; k0 += 32) {
        __syncthreads();
        // stage A: 128x32 f16, vectorized 16B
        #pragma unroll
        for (int p = 0; p < 2; ++p) {
            int e = (p * 256 + tid) * 8;
            int r = e >> 5, kq = e & 31;
            f16x8 v = *(const f16x8*)(A + (size_t)(m0 + r) * lda + k0 + kq);
            *(f16x8*)(&As[r][kq]) = v;
        }
        // stage B transposed: Bs[n][k] = Bsrc[(k0+k)*ldb + n], f32 -> f16
        #pragma unroll
        for (int p = 0; p < 4; ++p) {
            int k = p * 8 + (tid >> 5);
            int n = (tid & 31) * 4;
            float4 v = *(const float4*)(Bsrc + (size_t)(k0 + k) * ldb + n);
            Bs[n + 0][k] = (f16)v.x; Bs[n + 1][k] = (f16)v.y;
            Bs[n + 2][k] = (f16)v.z; Bs[n + 3][k] = (f16)v.w;
        }
        __syncthreads();
        int kq = (l >> 4) * 8;
        f16x8 a[4], b[4];
        #pragma unroll
        for (int i = 0; i < 4; ++i) a[i] = *(const f16x8*)(&As[wm * 64 + i * 16 + (l & 15)][kq]);
        #pragma unroll
        for (int j = 0; j < 4; ++j) b[j] = *(const f16x8*)(&Bs[wn * 64 + j * 16 + (l & 15)][kq]);
        #pragma unroll
        for (int i = 0; i < 4; ++i)
            #pragma unroll
            for (int j = 0; j < 4; ++j)
                acc[i][j] = __builtin_amdgcn_mfma_f32_16x16x32_f16(a[i], b[j], acc[i][j], 0, 0, 0);
    }
    int lr = (l >> 4) * 4, lc = l & 15;
    #pragma unroll
    for (int i = 0; i < 4; ++i) {
        #pragma unroll
        for (int j = 0; j < 4; ++j) {
            int gcol = wn * 64 + j * 16 + lc;
            float bia = bias[gcol];
            #pragma unroll
            for (int q = 0; q < 4; ++q) {
                int grow = m0 + wm * 64 + i * 16 + lr + q;
                proj[(size_t)grow * 3072 + outcol + gcol] = (f16)(acc[i][j][q] + bia);
            }
        }
    }
}

// ---------------- final FC: logits[b*T+t][v] = y[t][b] @ fcW + fcb, f32 out -------------
__launch_bounds__(256)
__global__ void gemm_fc(const f16* __restrict__ y, const float* __restrict__ W,
                        const float* __restrict__ bias, float* __restrict__ out) {
    __shared__ f16 As[128][40];
    __shared__ f16 Bs[128][40];
    int m0 = blockIdx.x * 128;
    int tid = threadIdx.x;
    int w = tid >> 6, l = tid & 63;
    int wm = w & 1, wn = w >> 1;   // N = 128 = 2*64
    f32x4 acc[4][4] = {};
    for (int k0 = 0; k0 < 2048; k0 += 32) {
        __syncthreads();
        #pragma unroll
        for (int p = 0; p < 2; ++p) {
            int e = (p * 256 + tid) * 8;
            int r = e >> 5, kq = e & 31;
            int grow = m0 + r;                 // row = b*256 + t
            int b = grow >> 8, t = grow & 255;
            f16x8 v = *(const f16x8*)(y + (size_t)(t * 32 + b) * 2048 + k0 + kq);
            *(f16x8*)(&As[r][kq]) = v;
        }
        #pragma unroll
        for (int p = 0; p < 4; ++p) {
            int k = p * 8 + (tid >> 5);
            int n = (tid & 31) * 4;
            float4 v = *(const float4*)(W + (size_t)(k0 + k) * 128 + n);
            Bs[n + 0][k] = (f16)v.x; Bs[n + 1][k] = (f16)v.y;
            Bs[n + 2][k] = (f16)v.z; Bs[n + 3][k] = (f16)v.w;
        }
        __syncthreads();
        int kq = (l >> 4) * 8;
        f16x8 a[4], b[4];
        #pragma unroll
        for (int i = 0; i < 4; ++i) a[i] = *(const f16x8*)(&As[wm * 64 + i * 16 + (l & 15)][kq]);
        #pragma unroll
        for (int j = 0; j < 4; ++j) b[j] = *(const f16x8*)(&Bs[wn * 64 + j * 16 + (l & 15)][kq]);
        #pragma unroll
        for (int i = 0; i < 4; ++i)
            #pragma unroll
            for (int j = 0; j < 4; ++j)
                acc[i][j] = __builtin_amdgcn_mfma_f32_16x16x32_f16(a[i], b[j], acc[i][j], 0, 0, 0);
    }
    int lr = (l >> 4) * 4, lc = l & 15;
    #pragma unroll
    for (int i = 0; i < 4; ++i) {
        #pragma unroll
        for (int j = 0; j < 4; ++j) {
            int gcol = wn * 64 + j * 16 + lc;
            float bia = bias[gcol];
            #pragma unroll
            for (int q = 0; q < 4; ++q) {
                int grow = m0 + wm * 64 + i * 16 + lr + q;
                out[(size_t)grow * 128 + gcol] = acc[i][j][q] + bia;
            }
        }
    }
}

// ---------------- recurrent bidirectional GRU layer (cooperative) ----------------
// 128 blocks x 256 threads. dir = bid>>6. Per block: 32 gate cols + 16 cand cols,
// recurrent weight slices resident in LDS as f16 (pitch 1032 to avoid bank conflicts).
__launch_bounds__(256)
__global__ void gru_layer(
    const f16* __restrict__ proj_fw, const f16* __restrict__ proj_bw,
    const float* __restrict__ Wgh_fw, const float* __restrict__ Wgh_bw,
    const float* __restrict__ Wch_fw, const float* __restrict__ Wch_bw,
    const float* __restrict__ h0_fw, const float* __restrict__ h0_bw,
    float* __restrict__ h32, f16* __restrict__ h16,
    f16* __restrict__ rh16, float* __restrict__ u32,
    f16* __restrict__ y, float* __restrict__ st_fw, float* __restrict__ st_bw)
{
    extern __shared__ char smem[];
    f16* Wg_lds = (f16*)smem;                       // [32][1032]
    f16* Wc_lds = (f16*)(smem + 32 * 1032 * 2);     // [16][1032]
    cg::grid_group grid = cg::this_grid();

    int bid = blockIdx.x;
    int dir = bid >> 6;
    int gcb = (bid & 63) * 32;   // gate col base (0..2047)
    int ccb = (bid & 63) * 16;   // cand col base (0..1023)
    int tid = threadIdx.x;

    const f16*  proj = dir ? proj_bw : proj_fw;
    const float* Wgh = dir ? Wgh_bw : Wgh_fw;
    const float* Wch = dir ? Wch_bw : Wch_fw;
    const float* h0  = dir ? h0_bw  : h0_fw;
    float* h32d  = h32  + dir * (NB * NU);
    f16*   h16d  = h16  + dir * (NB * NU);
    f16*   rh16d = rh16 + dir * (NB * NU);
    float* u32d  = u32  + dir * (NB * NU);

    // stage recurrent weight slices into LDS (f32 -> f16, transposed [col][k])
    {
        int j = tid & 31;
        for (int k = tid >> 5; k < NU; k += 8)
            Wg_lds[j * 1032 + k] = (f16)Wgh[(size_t)k * 2048 + gcb + j];
        int j2 = tid & 15;
        for (int k = tid >> 4; k < NU; k += 16)
            Wc_lds[j2 * 1032 + k] = (f16)Wch[(size_t)k * 1024 + ccb + j2];
    }
    // init h (partitioned across the 64 blocks of this dir)
    {
        int base = (bid & 63) * 512;
        for (int i = tid; i < 512; i += 256) {
            float v = h0[base + i];
            h32d[base + i] = v;
            h16d[base + i] = (f16)v;
        }
    }
    grid.sync();

    int w = tid >> 6, l = tid & 63;
    int lr = (l >> 4) * 4, lc = l & 15, kq = (l >> 4) * 8;

    for (int tl = 0; tl < NT; ++tl) {
        int td = dir ? (NT - 1 - tl) : tl;
        const f16* projrow = proj + (size_t)td * NB * 3072;

        // ---- phase A: ru = sigmoid(proj_g + h @ Wg_h); r*h and u to global ----
        {
            int wm = w & 1, wn = w >> 1;
            const f16* aptr = h16d + (wm * 16 + lc) * NU + kq;
            const f16* bptr = Wg_lds + (wn * 16 + lc) * 1032 + kq;
            f32x4 acc0 = {}, acc1 = {};
            #pragma unroll 4
            for (int kt = 0; kt < 32; kt += 2) {
                f16x8 a0 = *(const f16x8*)(aptr + kt * 32);
                f16x8 b0 = *(const f16x8*)(bptr + kt * 32);
                f16x8 a1 = *(const f16x8*)(aptr + kt * 32 + 32);
                f16x8 b1 = *(const f16x8*)(bptr + kt * 32 + 32);
                acc0 = __builtin_amdgcn_mfma_f32_16x16x32_f16(a0, b0, acc0, 0, 0, 0);
                acc1 = __builtin_amdgcn_mfma_f32_16x16x32_f16(a1, b1, acc1, 0, 0, 0);
            }
            f32x4 acc = acc0 + acc1;
            int gc = gcb + wn * 16 + lc;
            #pragma unroll
            for (int q = 0; q < 4; ++q) {
                int br = wm * 16 + lr + q;
                float pre = acc[q] + (float)projrow[(size_t)br * 3072 + gc];
                float sg = 1.f / (1.f + expf(-pre));
                if (gc < NU) {
                    float rh = sg * h32d[br * NU + gc];
                    rh16d[br * NU + gc] = (f16)rh;
                } else {
                    u32d[br * NU + gc - NU] = sg;
                }
            }
        }
        grid.sync();

        // ---- phase B: c = tanh(proj_c + (r*h) @ Wc_h); h = u*h + (1-u)*c ----
        if (w < 2) {
            int wm = w;
            const f16* aptr = rh16d + (wm * 16 + lc) * NU + kq;
            const f16* bptr = Wc_lds + lc * 1032 + kq;
            f32x4 acc0 = {}, acc1 = {};
            #pragma unroll 4
            for (int kt = 0; kt < 32; kt += 2) {
                f16x8 a0 = *(const f16x8*)(aptr + kt * 32);
                f16x8 b0 = *(const f16x8*)(bptr + kt * 32);
                f16x8 a1 = *(const f16x8*)(aptr + kt * 32 + 32);
                f16x8 b1 = *(const f16x8*)(bptr + kt * 32 + 32);
                acc0 = __builtin_amdgcn_mfma_f32_16x16x32_f16(a0, b0, acc0, 0, 0, 0);
                acc1 = __builtin_amdgcn_mfma_f32_16x16x32_f16(a1, b1, acc1, 0, 0, 0);
            }
            f32x4 acc = acc0 + acc1;
            int cc = ccb + lc;
            #pragma unroll
            for (int q = 0; q < 4; ++q) {
                int br = wm * 16 + lr + q;
                float pre = acc[q] + (float)projrow[(size_t)br * 3072 + 2048 + cc];
                float c = tanhf(pre);
                float u = u32d[br * NU + cc];
                float hold = h32d[br * NU + cc];
                float hn = u * hold + (1.f - u) * c;
                h32d[br * NU + cc] = hn;
                h16d[br * NU + cc] = (f16)hn;
                y[(size_t)(td * NB + br) * 2048 + dir * NU + cc] = (f16)hn;
                if (tl == NT - 1)
                    (dir ? st_bw : st_fw)[br * NU + cc] = hn;
            }
        }
        grid.sync();
    }
}

// ---------------- host launch ----------------
extern "C" void kernel_launch(void* const* d_in, const int* in_sizes, int n_in,
                              void* d_out, int out_size, void* d_ws, size_t ws_size,
                              hipStream_t stream) {
    const int*   x   = (const int*)  d_in[0];
    const float* emb = (const float*)d_in[1];
    const float* fcW = (const float*)d_in[2];
    const float* fcb = (const float*)d_in[3];
    float* out = (float*)d_out;

    char* ws = (char*)d_ws;
    size_t off = 0;
    f16* seq0   = (f16*)(ws + off); off += (size_t)8192 * 256 * 2;
    f16* ybuf0  = (f16*)(ws + off); off += (size_t)8192 * 2048 * 2;
    f16* ybuf1  = (f16*)(ws + off); off += (size_t)8192 * 2048 * 2;
    f16* projfw = (f16*)(ws + off); off += (size_t)8192 * 3072 * 2;
    f16* projbw = (f16*)(ws + off); off += (size_t)8192 * 3072 * 2;
    float* h32  = (float*)(ws + off); off += 2 * 32 * 1024 * 4;
    f16*   h16  = (f16*)(ws + off);   off += 2 * 32 * 1024 * 2;
    f16*   rh16 = (f16*)(ws + off);   off += 2 * 32 * 1024 * 2;
    float* u32  = (float*)(ws + off); off += 2 * 32 * 1024 * 4;

    hipFuncSetAttribute((const void*)gru_layer,
                        hipFuncAttributeMaxDynamicSharedMemorySize, 99072);

    embed_kernel<<<dim3(8192), dim3(256), 0, stream>>>(x, emb, seq0);

    const f16* lin = seq0; int lda = 256, K = 256;
    f16* ybufs[2] = {ybuf0, ybuf1};
    for (int l = 0; l < 3; ++l) {
        const float* Wg_fw = (const float*)d_in[4 + l * 10 + 0];
        const float* bg_fw = (const float*)d_in[4 + l * 10 + 1];
        const float* Wc_fw = (const float*)d_in[4 + l * 10 + 2];
        const float* bc_fw = (const float*)d_in[4 + l * 10 + 3];
        const float* h0_fw = (const float*)d_in[4 + l * 10 + 4];
        const float* Wg_bw = (const float*)d_in[4 + l * 10 + 5];
        const float* bg_bw = (const float*)d_in[4 + l * 10 + 6];
        const float* Wc_bw = (const float*)d_in[4 + l * 10 + 7];
        const float* bc_bw = (const float*)d_in[4 + l * 10 + 8];
        const float* h0_bw = (const float*)d_in[4 + l * 10 + 9];
        int din = (l == 0) ? 256 : 2048;

        gemm_proj<<<dim3(64, 24), dim3(256), 0, stream>>>(lin, lda, K, Wg_fw, Wc_fw, bg_fw, bc_fw, projfw);
        gemm_proj<<<dim3(64, 24), dim3(256), 0, stream>>>(lin, lda, K, Wg_bw, Wc_bw, bg_bw, bc_bw, projbw);

        const float* Wgh_fw = Wg_fw + (size_t)din * 2048;
        const float* Wgh_bw = Wg_bw + (size_t)din * 2048;
        const float* Wch_fw = Wc_fw + (size_t)din * 1024;
        const float* Wch_bw = Wc_bw + (size_t)din * 1024;
        f16* yout = ybufs[l & 1];
        float* stfw = out + 1048576 + l * 32768;
        float* stbw = out + 1048576 + 98304 + l * 32768;
        const f16* pfw = projfw; const f16* pbw = projbw;
        void* args[] = {
            (void*)&pfw, (void*)&pbw,
            (void*)&Wgh_fw, (void*)&Wgh_bw, (void*)&Wch_fw, (void*)&Wch_bw,
            (void*)&h0_fw, (void*)&h0_bw,
            (void*)&h32, (void*)&h16, (void*)&rh16, (void*)&u32,
            (void*)&yout, (void*)&stfw, (void*)&stbw };
        hipLaunchCooperativeKernel((const void*)gru_layer, dim3(128), dim3(256),
                                   args, (unsigned)99072, stream);
        lin = yout; lda = 2048; K = 2048;
    }

    gemm_fc<<<dim3(64), dim3(256), 0, stream>>>(ybufs[0], fcW, fcb, out);
}

// Round 2
// 18466.785 us; speedup vs baseline: 1.8919x; 1.8919x over previous
//
#include <hip/hip_runtime.h>

typedef _Float16 f16;
typedef _Float16 f16x8 __attribute__((ext_vector_type(8)));
typedef float f32x4 __attribute__((ext_vector_type(4)));

#define NB 32
#define NT 256
#define NE 256
#define NU 1024
#define NV 128

// ---------- agent-coherent (cross-XCD, L3-level) load/store helpers ----------
__device__ __forceinline__ unsigned long long cload64(const f16* p) {
    return __hip_atomic_load((const unsigned long long*)p, __ATOMIC_RELAXED,
                             __HIP_MEMORY_SCOPE_AGENT);
}
__device__ __forceinline__ float cloadf(const float* p) {
    return __hip_atomic_load(p, __ATOMIC_RELAXED, __HIP_MEMORY_SCOPE_AGENT);
}
__device__ __forceinline__ void cstoref(float* p, float v) {
    __hip_atomic_store(p, v, __ATOMIC_RELAXED, __HIP_MEMORY_SCOPE_AGENT);
}
__device__ __forceinline__ void cstore16(f16* p, f16 v) {
    __hip_atomic_store((unsigned short*)p, __builtin_bit_cast(unsigned short, v),
                       __ATOMIC_RELAXED, __HIP_MEMORY_SCOPE_AGENT);
}

// ---------- lightweight grid barrier: 8 spread counters at L3, no L2 flush ----------
// cnt: 8 counters, 128B apart. Block bid adds to cnt[bid&7]; each counter gets 16
// increments per barrier (128 blocks). Threads 0..7 spin on their counter.
__device__ __forceinline__ void gbarrier(unsigned* cnt, unsigned target16) {
    asm volatile("s_waitcnt vmcnt(0)" ::: "memory");  // my coherent stores are at L3
    __syncthreads();                                   // whole block drained
    int tid = threadIdx.x;
    if (tid == 0)
        __hip_atomic_fetch_add(&cnt[(blockIdx.x & 7) * 32], 1u,
                               __ATOMIC_RELAXED, __HIP_MEMORY_SCOPE_AGENT);
    if (tid < 8) {
        int iter = 0;
        while (__hip_atomic_load(&cnt[tid * 32], __ATOMIC_RELAXED,
                                 __HIP_MEMORY_SCOPE_AGENT) < target16) {
            __builtin_amdgcn_s_sleep(2);
            if (++iter > (1 << 14)) break;  // failsafe: fail visibly, don't hang
        }
    }
    __syncthreads();
}

// ---------------- embedding: seq0[t*NB+b][e] = emb[x[b][t]][e] (f16) ----------------
__global__ void embed_kernel(const int* __restrict__ x, const float* __restrict__ emb,
                             f16* __restrict__ seq0) {
    int row = blockIdx.x;           // t*NB + b
    int t = row >> 5, b = row & 31;
    int e = threadIdx.x;            // 256 threads == NE
    int idx = x[b * NT + t];
    seq0[row * NE + e] = (f16)emb[idx * NE + e];
}

// ---------------- input-projection GEMM: proj[row][0:2048]=x@Wg_x+bg, [2048:3072]=x@Wc_x+bc ----
__launch_bounds__(256)
__global__ void gemm_proj(const f16* __restrict__ A, int lda, int K,
                          const float* __restrict__ Wg, const float* __restrict__ Wc,
                          const float* __restrict__ bg, const float* __restrict__ bc,
                          f16* __restrict__ proj) {
    __shared__ f16 As[128][40];
    __shared__ f16 Bs[128][40];
    int cb = blockIdx.y;
    const float* Bsrc; int ldb, outcol; const float* bias;
    if (cb < 16) { Bsrc = Wg + cb * 128; ldb = 2 * NU; outcol = cb * 128; bias = bg + cb * 128; }
    else { Bsrc = Wc + (cb - 16) * 128; ldb = NU; outcol = 2 * NU + (cb - 16) * 128; bias = bc + (cb - 16) * 128; }
    int m0 = blockIdx.x * 128;
    int tid = threadIdx.x;
    int w = tid >> 6, l = tid & 63;
    int wm = w & 1, wn = w >> 1;
    f32x4 acc[4][4] = {};
    for (int k0 = 0; k0 < K; k0 += 32) {
        __syncthreads();
        #pragma unroll
        for (int p = 0; p < 2; ++p) {
            int e = (p * 256 + tid) * 8;
            int r = e >> 5, kq = e & 31;
            f16x8 v = *(const f16x8*)(A + (size_t)(m0 + r) * lda + k0 + kq);
            *(f16x8*)(&As[r][kq]) = v;
        }
        #pragma unroll
        for (int p = 0; p < 4; ++p) {
            int k = p * 8 + (tid >> 5);
            int n = (tid & 31) * 4;
            float4 v = *(const float4*)(Bsrc + (size_t)(k0 + k) * ldb + n);
            Bs[n + 0][k] = (f16)v.x; Bs[n + 1][k] = (f16)v.y;
            Bs[n + 2][k] = (f16)v.z; Bs[n + 3][k] = (f16)v.w;
        }
        __syncthreads();
        int kq = (l >> 4) * 8;
        f16x8 a[4], b[4];
        #pragma unroll
        for (int i = 0; i < 4; ++i) a[i] = *(const f16x8*)(&As[wm * 64 + i * 16 + (l & 15)][kq]);
        #pragma unroll
        for (int j = 0; j < 4; ++j) b[j] = *(const f16x8*)(&Bs[wn * 64 + j * 16 + (l & 15)][kq]);
        #pragma unroll
        for (int i = 0; i < 4; ++i)
            #pragma unroll
            for (int j = 0; j < 4; ++j)
                acc[i][j] = __builtin_amdgcn_mfma_f32_16x16x32_f16(a[i], b[j], acc[i][j], 0, 0, 0);
    }
    int lr = (l >> 4) * 4, lc = l & 15;
    #pragma unroll
    for (int i = 0; i < 4; ++i) {
        #pragma unroll
        for (int j = 0; j < 4; ++j) {
            int gcol = wn * 64 + j * 16 + lc;
            float bia = bias[gcol];
            #pragma unroll
            for (int q = 0; q < 4; ++q) {
                int grow = m0 + wm * 64 + i * 16 + lr + q;
                proj[(size_t)grow * 3072 + outcol + gcol] = (f16)(acc[i][j][q] + bia);
            }
        }
    }
}

// ---------------- final FC: logits[b*T+t][v] = y[t][b] @ fcW + fcb, f32 out -------------
__launch_bounds__(256)
__global__ void gemm_fc(const f16* __restrict__ y, const float* __restrict__ W,
                        const float* __restrict__ bias, float* __restrict__ out) {
    __shared__ f16 As[128][40];
    __shared__ f16 Bs[128][40];
    int m0 = blockIdx.x * 128;
    int tid = threadIdx.x;
    int w = tid >> 6, l = tid & 63;
    int wm = w & 1, wn = w >> 1;
    f32x4 acc[4][4] = {};
    for (int k0 = 0; k0 < 2048; k0 += 32) {
        __syncthreads();
        #pragma unroll
        for (int p = 0; p < 2; ++p) {
            int e = (p * 256 + tid) * 8;
            int r = e >> 5, kq = e & 31;
            int grow = m0 + r;                 // row = b*256 + t
            int b = grow >> 8, t = grow & 255;
            f16x8 v = *(const f16x8*)(y + (size_t)(t * 32 + b) * 2048 + k0 + kq);
            *(f16x8*)(&As[r][kq]) = v;
        }
        #pragma unroll
        for (int p = 0; p < 4; ++p) {
            int k = p * 8 + (tid >> 5);
            int n = (tid & 31) * 4;
            float4 v = *(const float4*)(W + (size_t)(k0 + k) * 128 + n);
            Bs[n + 0][k] = (f16)v.x; Bs[n + 1][k] = (f16)v.y;
            Bs[n + 2][k] = (f16)v.z; Bs[n + 3][k] = (f16)v.w;
        }
        __syncthreads();
        int kq = (l >> 4) * 8;
        f16x8 a[4], b[4];
        #pragma unroll
        for (int i = 0; i < 4; ++i) a[i] = *(const f16x8*)(&As[wm * 64 + i * 16 + (l & 15)][kq]);
        #pragma unroll
        for (int j = 0; j < 4; ++j) b[j] = *(const f16x8*)(&Bs[wn * 64 + j * 16 + (l & 15)][kq]);
        #pragma unroll
        for (int i = 0; i < 4; ++i)
            #pragma unroll
            for (int j = 0; j < 4; ++j)
                acc[i][j] = __builtin_amdgcn_mfma_f32_16x16x32_f16(a[i], b[j], acc[i][j], 0, 0, 0);
    }
    int lr = (l >> 4) * 4, lc = l & 15;
    #pragma unroll
    for (int i = 0; i < 4; ++i) {
        #pragma unroll
        for (int j = 0; j < 4; ++j) {
            int gcol = wn * 64 + j * 16 + lc;
            float bia = bias[gcol];
            #pragma unroll
            for (int q = 0; q < 4; ++q) {
                int grow = m0 + wm * 64 + i * 16 + lr + q;
                out[(size_t)grow * 128 + gcol] = acc[i][j][q] + bia;
            }
        }
    }
}

// ---------------- recurrent bidirectional GRU layer (cooperative, custom barrier) ----------
__launch_bounds__(256)
__global__ void gru_layer(
    const f16* __restrict__ proj_fw, const f16* __restrict__ proj_bw,
    const float* __restrict__ Wgh_fw, const float* __restrict__ Wgh_bw,
    const float* __restrict__ Wch_fw, const float* __restrict__ Wch_bw,
    const float* __restrict__ h0_fw, const float* __restrict__ h0_bw,
    float* __restrict__ h32, f16* __restrict__ h16,
    f16* __restrict__ rh16, float* __restrict__ u32,
    f16* __restrict__ y, float* __restrict__ st_fw, float* __restrict__ st_bw,
    unsigned* __restrict__ cnt)
{
    extern __shared__ char smem[];
    f16* Wg_lds = (f16*)smem;                       // [32][1032]
    f16* Wc_lds = (f16*)(smem + 32 * 1032 * 2);     // [16][1032]

    int bid = blockIdx.x;
    int dir = bid >> 6;
    int gcb = (bid & 63) * 32;   // gate col base (0..2047)
    int ccb = (bid & 63) * 16;   // cand col base (0..1023)
    int tid = threadIdx.x;

    const f16*  proj = dir ? proj_bw : proj_fw;
    const float* Wgh = dir ? Wgh_bw : Wgh_fw;
    const float* Wch = dir ? Wch_bw : Wch_fw;
    const float* h0  = dir ? h0_bw  : h0_fw;
    float* h32d  = h32  + dir * (NB * NU);
    f16*   h16d  = h16  + dir * (NB * NU);
    f16*   rh16d = rh16 + dir * (NB * NU);
    float* u32d  = u32  + dir * (NB * NU);

    // stage recurrent weight slices into LDS (f32 -> f16, transposed [col][k])
    {
        int j = tid & 31;
        for (int k = tid >> 5; k < NU; k += 8)
            Wg_lds[j * 1032 + k] = (f16)Wgh[(size_t)k * 2048 + gcb + j];
        int j2 = tid & 15;
        for (int k = tid >> 4; k < NU; k += 16)
            Wc_lds[j2 * 1032 + k] = (f16)Wch[(size_t)k * 1024 + ccb + j2];
    }
    // init h (partitioned across the 64 blocks of this dir) — coherent stores
    {
        int base = (bid & 63) * 512;
        for (int i = tid; i < 512; i += 256) {
            float v = h0[base + i];
            cstoref(h32d + base + i, v);
            cstore16(h16d + base + i, (f16)v);
        }
    }
    unsigned bc = 1;
    gbarrier(cnt, bc * 16u);

    int w = tid >> 6, l = tid & 63;
    int lr = (l >> 4) * 4, lc = l & 15, kq = (l >> 4) * 8;

    for (int tl = 0; tl < NT; ++tl) {
        int td = dir ? (NT - 1 - tl) : tl;
        const f16* projrow = proj + (size_t)td * NB * 3072;

        // ---- phase A: ru = sigmoid(proj_g + h @ Wg_h); r*h and u to global ----
        {
            int wm = w & 1, wn = w >> 1;
            const f16* aptr = h16d + (wm * 16 + lc) * NU + kq;
            const f16* bptr = Wg_lds + (wn * 16 + lc) * 1032 + kq;
            f32x4 acc0 = {}, acc1 = {};
            #pragma unroll
            for (int kt = 0; kt < 32; kt += 2) {
                union { unsigned long long q[2]; f16x8 v; } a0, a1;
                a0.q[0] = cload64(aptr + kt * 32);
                a0.q[1] = cload64(aptr + kt * 32 + 4);
                a1.q[0] = cload64(aptr + kt * 32 + 32);
                a1.q[1] = cload64(aptr + kt * 32 + 36);
                f16x8 b0 = *(const f16x8*)(bptr + kt * 32);
                f16x8 b1 = *(const f16x8*)(bptr + kt * 32 + 32);
                acc0 = __builtin_amdgcn_mfma_f32_16x16x32_f16(a0.v, b0, acc0, 0, 0, 0);
                acc1 = __builtin_amdgcn_mfma_f32_16x16x32_f16(a1.v, b1, acc1, 0, 0, 0);
            }
            f32x4 acc = acc0 + acc1;
            int gc = gcb + wn * 16 + lc;
            #pragma unroll
            for (int q = 0; q < 4; ++q) {
                int br = wm * 16 + lr + q;
                float pre = acc[q] + (float)projrow[(size_t)br * 3072 + gc];
                float sg = 1.f / (1.f + expf(-pre));
                if (gc < NU) {
                    float hv = cloadf(h32d + br * NU + gc);
                    cstore16(rh16d + br * NU + gc, (f16)(sg * hv));
                } else {
                    cstoref(u32d + br * NU + gc - NU, sg);
                }
            }
        }
        ++bc; gbarrier(cnt, bc * 16u);

        // ---- phase B: c = tanh(proj_c + (r*h) @ Wc_h); h = u*h + (1-u)*c ----
        if (w < 2) {
            int wm = w;
            const f16* aptr = rh16d + (wm * 16 + lc) * NU + kq;
            const f16* bptr = Wc_lds + lc * 1032 + kq;
            f32x4 acc0 = {}, acc1 = {};
            #pragma unroll
            for (int kt = 0; kt < 32; kt += 2) {
                union { unsigned long long q[2]; f16x8 v; } a0, a1;
                a0.q[0] = cload64(aptr + kt * 32);
                a0.q[1] = cload64(aptr + kt * 32 + 4);
                a1.q[0] = cload64(aptr + kt * 32 + 32);
                a1.q[1] = cload64(aptr + kt * 32 + 36);
                f16x8 b0 = *(const f16x8*)(bptr + kt * 32);
                f16x8 b1 = *(const f16x8*)(bptr + kt * 32 + 32);
                acc0 = __builtin_amdgcn_mfma_f32_16x16x32_f16(a0.v, b0, acc0, 0, 0, 0);
                acc1 = __builtin_amdgcn_mfma_f32_16x16x32_f16(a1.v, b1, acc1, 0, 0, 0);
            }
            f32x4 acc = acc0 + acc1;
            int cc = ccb + lc;
            #pragma unroll
            for (int q = 0; q < 4; ++q) {
                int br = wm * 16 + lr + q;
                float pre = acc[q] + (float)projrow[(size_t)br * 3072 + 2048 + cc];
                float c = tanhf(pre);
                float u = cloadf(u32d + br * NU + cc);
                float hold = cloadf(h32d + br * NU + cc);
                float hn = u * hold + (1.f - u) * c;
                cstoref(h32d + br * NU + cc, hn);
                cstore16(h16d + br * NU + cc, (f16)hn);
                y[(size_t)(td * NB + br) * 2048 + dir * NU + cc] = (f16)hn;
                if (tl == NT - 1)
                    (dir ? st_bw : st_fw)[br * NU + cc] = hn;
            }
        }
        ++bc; gbarrier(cnt, bc * 16u);
    }
}

// ---------------- host launch ----------------
extern "C" void kernel_launch(void* const* d_in, const int* in_sizes, int n_in,
                              void* d_out, int out_size, void* d_ws, size_t ws_size,
                              hipStream_t stream) {
    const int*   x   = (const int*)  d_in[0];
    const float* emb = (const float*)d_in[1];
    const float* fcW = (const float*)d_in[2];
    const float* fcb = (const float*)d_in[3];
    float* out = (float*)d_out;

    char* ws = (char*)d_ws;
    size_t off = 0;
    f16* seq0   = (f16*)(ws + off); off += (size_t)8192 * 256 * 2;
    f16* ybuf0  = (f16*)(ws + off); off += (size_t)8192 * 2048 * 2;
    f16* ybuf1  = (f16*)(ws + off); off += (size_t)8192 * 2048 * 2;
    f16* projfw = (f16*)(ws + off); off += (size_t)8192 * 3072 * 2;
    f16* projbw = (f16*)(ws + off); off += (size_t)8192 * 3072 * 2;
    float* h32  = (float*)(ws + off); off += 2 * 32 * 1024 * 4;
    f16*   h16  = (f16*)(ws + off);   off += 2 * 32 * 1024 * 2;
    f16*   rh16 = (f16*)(ws + off);   off += 2 * 32 * 1024 * 2;
    float* u32  = (float*)(ws + off); off += 2 * 32 * 1024 * 4;
    unsigned* ctrl = (unsigned*)(ws + off); off += 3 * 1024;

    hipFuncSetAttribute((const void*)gru_layer,
                        hipFuncAttributeMaxDynamicSharedMemorySize, 99072);

    hipMemsetAsync(ctrl, 0, 3 * 1024, stream);
    embed_kernel<<<dim3(8192), dim3(256), 0, stream>>>(x, emb, seq0);

    const f16* lin = seq0; int lda = 256, K = 256;
    f16* ybufs[2] = {ybuf0, ybuf1};
    for (int l = 0; l < 3; ++l) {
        const float* Wg_fw = (const float*)d_in[4 + l * 10 + 0];
        const float* bg_fw = (const float*)d_in[4 + l * 10 + 1];
        const float* Wc_fw = (const float*)d_in[4 + l * 10 + 2];
        const float* bc_fw = (const float*)d_in[4 + l * 10 + 3];
        const float* h0_fw = (const float*)d_in[4 + l * 10 + 4];
        const float* Wg_bw = (const float*)d_in[4 + l * 10 + 5];
        const float* bg_bw = (const float*)d_in[4 + l * 10 + 6];
        const float* Wc_bw = (const float*)d_in[4 + l * 10 + 7];
        const float* bc_bw = (const float*)d_in[4 + l * 10 + 8];
        const float* h0_bw = (const float*)d_in[4 + l * 10 + 9];
        int din = (l == 0) ? 256 : 2048;

        gemm_proj<<<dim3(64, 24), dim3(256), 0, stream>>>(lin, lda, K, Wg_fw, Wc_fw, bg_fw, bc_fw, projfw);
        gemm_proj<<<dim3(64, 24), dim3(256), 0, stream>>>(lin, lda, K, Wg_bw, Wc_bw, bg_bw, bc_bw, projbw);

        const float* Wgh_fw = Wg_fw + (size_t)din * 2048;
        const float* Wgh_bw = Wg_bw + (size_t)din * 2048;
        const float* Wch_fw = Wc_fw + (size_t)din * 1024;
        const float* Wch_bw = Wc_bw + (size_t)din * 1024;
        f16* yout = ybufs[l & 1];
        float* stfw = out + 1048576 + l * 32768;
        float* stbw = out + 1048576 + 98304 + l * 32768;
        const f16* pfw = projfw; const f16* pbw = projbw;
        unsigned* cnt = ctrl + l * 256;
        void* args[] = {
            (void*)&pfw, (void*)&pbw,
            (void*)&Wgh_fw, (void*)&Wgh_bw, (void*)&Wch_fw, (void*)&Wch_bw,
            (void*)&h0_fw, (void*)&h0_bw,
            (void*)&h32, (void*)&h16, (void*)&rh16, (void*)&u32,
            (void*)&yout, (void*)&stfw, (void*)&stbw, (void*)&cnt };
        hipLaunchCooperativeKernel((const void*)gru_layer, dim3(128), dim3(256),
                                   args, (unsigned)99072, stream);
        lin = yout; lda = 2048; K = 2048;
    }

    gemm_fc<<<dim3(64), dim3(256), 0, stream>>>(ybufs[0], fcW, fcb, out);
}

// Round 5
// 13397.177 us; speedup vs baseline: 2.6079x; 1.3784x over previous
//
#include <hip/hip_runtime.h>

typedef _Float16 f16;
typedef _Float16 f16x4 __attribute__((ext_vector_type(4)));
typedef _Float16 f16x8 __attribute__((ext_vector_type(8)));
typedef float f32x4 __attribute__((ext_vector_type(4)));

#define NB 32
#define NT 256
#define NE 256
#define NU 1024
#define NV 128

// ---------- agent-coherent (cross-XCD, L3-level) load/store helpers ----------
__device__ __forceinline__ unsigned long long cload64(const f16* p) {
    return __hip_atomic_load((const unsigned long long*)p, __ATOMIC_RELAXED,
                             __HIP_MEMORY_SCOPE_AGENT);
}
__device__ __forceinline__ float cloadf(const float* p) {
    return __hip_atomic_load(p, __ATOMIC_RELAXED, __HIP_MEMORY_SCOPE_AGENT);
}
__device__ __forceinline__ void cstoref(float* p, float v) {
    __hip_atomic_store(p, v, __ATOMIC_RELAXED, __HIP_MEMORY_SCOPE_AGENT);
}
__device__ __forceinline__ void cstore16(f16* p, f16 v) {
    __hip_atomic_store((unsigned short*)p, __builtin_bit_cast(unsigned short, v),
                       __ATOMIC_RELAXED, __HIP_MEMORY_SCOPE_AGENT);
}

// ---------- lightweight grid barrier (round-2 proven): 8 spread counters at L3 ----------
__device__ __forceinline__ void gbarrier(unsigned* cnt, unsigned target16) {
    asm volatile("s_waitcnt vmcnt(0)" ::: "memory");  // coherent stores drained to L3
    __syncthreads();
    if (threadIdx.x == 0)
        __hip_atomic_fetch_add(&cnt[(blockIdx.x & 7) * 32], 1u,
                               __ATOMIC_RELAXED, __HIP_MEMORY_SCOPE_AGENT);
    if (threadIdx.x < 8) {
        int it = 0;
        while (__hip_atomic_load(&cnt[threadIdx.x * 32], __ATOMIC_RELAXED,
                                 __HIP_MEMORY_SCOPE_AGENT) < target16) {
            __builtin_amdgcn_s_sleep(2);
            if (++it > (1 << 14)) break;  // failsafe: fail visibly, don't hang
        }
    }
    __syncthreads();
}

// ---------------- embedding ----------------
__global__ void embed_kernel(const int* __restrict__ x, const float* __restrict__ emb,
                             f16* __restrict__ seq0) {
    int row = blockIdx.x;           // t*NB + b
    int t = row >> 5, b = row & 31;
    int e = threadIdx.x;
    int idx = x[b * NT + t];
    seq0[row * NE + e] = (f16)emb[idx * NE + e];
}

// ---------------- input-projection GEMM ----------------
__launch_bounds__(256)
__global__ void gemm_proj(const f16* __restrict__ A, int lda, int K,
                          const float* __restrict__ Wg, const float* __restrict__ Wc,
                          const float* __restrict__ bg, const float* __restrict__ bc,
                          f16* __restrict__ proj) {
    __shared__ f16 As[128][40];
    __shared__ f16 Bs[128][40];
    int cb = blockIdx.y;
    const float* Bsrc; int ldb, outcol; const float* bias;
    if (cb < 16) { Bsrc = Wg + cb * 128; ldb = 2 * NU; outcol = cb * 128; bias = bg + cb * 128; }
    else { Bsrc = Wc + (cb - 16) * 128; ldb = NU; outcol = 2 * NU + (cb - 16) * 128; bias = bc + (cb - 16) * 128; }
    int m0 = blockIdx.x * 128;
    int tid = threadIdx.x;
    int w = tid >> 6, l = tid & 63;
    int wm = w & 1, wn = w >> 1;
    f32x4 acc[4][4] = {};
    for (int k0 = 0; k0 < K; k0 += 32) {
        __syncthreads();
        #pragma unroll
        for (int p = 0; p < 2; ++p) {
            int e = (p * 256 + tid) * 8;
            int r = e >> 5, kq = e & 31;
            f16x8 v = *(const f16x8*)(A + (size_t)(m0 + r) * lda + k0 + kq);
            *(f16x8*)(&As[r][kq]) = v;
        }
        #pragma unroll
        for (int p = 0; p < 4; ++p) {
            int k = p * 8 + (tid >> 5);
            int n = (tid & 31) * 4;
            float4 v = *(const float4*)(Bsrc + (size_t)(k0 + k) * ldb + n);
            Bs[n + 0][k] = (f16)v.x; Bs[n + 1][k] = (f16)v.y;
            Bs[n + 2][k] = (f16)v.z; Bs[n + 3][k] = (f16)v.w;
        }
        __syncthreads();
        int kq = (l >> 4) * 8;
        f16x8 a[4], b[4];
        #pragma unroll
        for (int i = 0; i < 4; ++i) a[i] = *(const f16x8*)(&As[wm * 64 + i * 16 + (l & 15)][kq]);
        #pragma unroll
        for (int j = 0; j < 4; ++j) b[j] = *(const f16x8*)(&Bs[wn * 64 + j * 16 + (l & 15)][kq]);
        #pragma unroll
        for (int i = 0; i < 4; ++i)
            #pragma unroll
            for (int j = 0; j < 4; ++j)
                acc[i][j] = __builtin_amdgcn_mfma_f32_16x16x32_f16(a[i], b[j], acc[i][j], 0, 0, 0);
    }
    int lr = (l >> 4) * 4, lc = l & 15;
    #pragma unroll
    for (int i = 0; i < 4; ++i) {
        #pragma unroll
        for (int j = 0; j < 4; ++j) {
            int gcol = wn * 64 + j * 16 + lc;
            float bia = bias[gcol];
            #pragma unroll
            for (int q = 0; q < 4; ++q) {
                int grow = m0 + wm * 64 + i * 16 + lr + q;
                proj[(size_t)grow * 3072 + outcol + gcol] = (f16)(acc[i][j][q] + bia);
            }
        }
    }
}

// ---------------- final FC ----------------
__launch_bounds__(256)
__global__ void gemm_fc(const f16* __restrict__ y, const float* __restrict__ W,
                        const float* __restrict__ bias, float* __restrict__ out) {
    __shared__ f16 As[128][40];
    __shared__ f16 Bs[128][40];
    int m0 = blockIdx.x * 128;
    int tid = threadIdx.x;
    int w = tid >> 6, l = tid & 63;
    int wm = w & 1, wn = w >> 1;
    f32x4 acc[4][4] = {};
    for (int k0 = 0; k0 < 2048; k0 += 32) {
        __syncthreads();
        #pragma unroll
        for (int p = 0; p < 2; ++p) {
            int e = (p * 256 + tid) * 8;
            int r = e >> 5, kq = e & 31;
            int grow = m0 + r;                 // row = b*256 + t
            int b = grow >> 8, t = grow & 255;
            f16x8 v = *(const f16x8*)(y + (size_t)(t * 32 + b) * 2048 + k0 + kq);
            *(f16x8*)(&As[r][kq]) = v;
        }
        #pragma unroll
        for (int p = 0; p < 4; ++p) {
            int k = p * 8 + (tid >> 5);
            int n = (tid & 31) * 4;
            float4 v = *(const float4*)(W + (size_t)(k0 + k) * 128 + n);
            Bs[n + 0][k] = (f16)v.x; Bs[n + 1][k] = (f16)v.y;
            Bs[n + 2][k] = (f16)v.z; Bs[n + 3][k] = (f16)v.w;
        }
        __syncthreads();
        int kq = (l >> 4) * 8;
        f16x8 a[4], b[4];
        #pragma unroll
        for (int i = 0; i < 4; ++i) a[i] = *(const f16x8*)(&As[wm * 64 + i * 16 + (l & 15)][kq]);
        #pragma unroll
        for (int j = 0; j < 4; ++j) b[j] = *(const f16x8*)(&Bs[wn * 64 + j * 16 + (l & 15)][kq]);
        #pragma unroll
        for (int i = 0; i < 4; ++i)
            #pragma unroll
            for (int j = 0; j < 4; ++j)
                acc[i][j] = __builtin_amdgcn_mfma_f32_16x16x32_f16(a[i], b[j], acc[i][j], 0, 0, 0);
    }
    int lr = (l >> 4) * 4, lc = l & 15;
    #pragma unroll
    for (int i = 0; i < 4; ++i) {
        #pragma unroll
        for (int j = 0; j < 4; ++j) {
            int gcol = wn * 64 + j * 16 + lc;
            float bia = bias[gcol];
            #pragma unroll
            for (int q = 0; q < 4; ++q) {
                int grow = m0 + wm * 64 + i * 16 + lr + q;
                out[(size_t)grow * 128 + gcol] = acc[i][j][q] + bia;
            }
        }
    }
}

// ---------------- recurrent bidirectional GRU layer ----------------
// r2 skeleton + coalesced LDS staging of A-operands. Typed f16 LDS only.
// LDS: stage[32][1032] f16 (66048B) + Wc[16][1032] f16 (33024B) = 99072B.
// Wg slice in registers (exonerated by r3/r4 identical-output analysis).
// Launched NORMALLY (not cooperative) — 128 blocks <= 256 CUs co-resident.
__launch_bounds__(256)
__global__ void gru_layer(
    const f16* __restrict__ proj_fw, const f16* __restrict__ proj_bw,
    const float* __restrict__ Wgh_fw, const float* __restrict__ Wgh_bw,
    const float* __restrict__ Wch_fw, const float* __restrict__ Wch_bw,
    const float* __restrict__ h0_fw, const float* __restrict__ h0_bw,
    float* __restrict__ h32, f16* __restrict__ h16,
    f16* __restrict__ rh16, float* __restrict__ u32,
    f16* __restrict__ y, float* __restrict__ st_fw, float* __restrict__ st_bw,
    unsigned* __restrict__ cnt)
{
    extern __shared__ f16 smem[];
    f16* stg    = smem;             // [32][1032]
    f16* Wc_lds = smem + 32 * 1032; // [16][1032]

    int bid = blockIdx.x, tid = threadIdx.x;
    int dir = bid >> 6, lb = bid & 63;
    int gcb = lb * 32;   // gate col base (0..2047)
    int ccb = lb * 16;   // cand col base (0..1023)

    const f16*  proj = dir ? proj_bw : proj_fw;
    const float* Wgh = dir ? Wgh_bw : Wgh_fw;
    const float* Wch = dir ? Wch_bw : Wch_fw;
    const float* h0  = dir ? h0_bw  : h0_fw;
    float* h32d  = h32  + dir * (NB * NU);
    f16*   h16d  = h16  + dir * (NB * NU);
    f16*   rh16d = rh16 + dir * (NB * NU);
    float* u32d  = u32  + dir * (NB * NU);

    int w = tid >> 6, l = tid & 63;
    int lc = l & 15, lr = (l >> 4) * 4, kq = (l >> 4) * 8;
    int wm = w & 1, wn = w >> 1;

    // ---- Wc slice into LDS (r2 verbatim) ----
    {
        int j2 = tid & 15;
        for (int k = tid >> 4; k < NU; k += 16)
            Wc_lds[j2 * 1032 + k] = (f16)Wch[(size_t)k * 1024 + ccb + j2];
    }

    // ---- Wg fragments -> registers (values == r2's Wg_lds reads) ----
    f16x8 wgf[32];
    {
        int col = gcb + wn * 16 + lc;
        #pragma unroll
        for (int kt = 0; kt < 32; ++kt) {
            f16x8 t;
            #pragma unroll
            for (int e = 0; e < 8; ++e)
                t[e] = (f16)Wgh[(size_t)(kt * 32 + kq + e) * 2048 + col];
            wgf[kt] = t;
        }
    }

    // ---- init h (r2 verbatim) ----
    {
        int base = lb * 512;
        for (int i = tid; i < 512; i += 256) {
            float v = h0[base + i];
            cstoref(h32d + base + i, v);
            cstore16(h16d + base + i, (f16)v);
        }
    }
    unsigned bc = 1;
    gbarrier(cnt, bc * 16u);

    for (int tl = 0; tl < NT; ++tl) {
        int td = dir ? (NT - 1 - tl) : tl;
        const f16* projrow = proj + (size_t)td * NB * 3072;

        // ---- stage h16d (64KB) coalesced -> LDS stage[row][0..1023] ----
        #pragma unroll
        for (int qt = 0; qt < 4; ++qt) {
            union { unsigned long long q; f16x4 h; } v[8];
            #pragma unroll
            for (int i = 0; i < 8; ++i)
                v[i].q = cload64(h16d + (qt * 8 + i) * NU + tid * 4);
            #pragma unroll
            for (int i = 0; i < 8; ++i)
                *(f16x4*)(&stg[(qt * 8 + i) * 1032 + tid * 4]) = v[i].h;
        }
        __syncthreads();

        // ---- phase A: ru = sigmoid(proj_g + h @ Wg_h) ----
        {
            const f16* ap = &stg[(wm * 16 + lc) * 1032 + kq];
            f32x4 acc0 = {}, acc1 = {};
            #pragma unroll
            for (int kt = 0; kt < 32; kt += 2) {
                f16x8 a0 = *(const f16x8*)(ap + kt * 32);
                f16x8 a1 = *(const f16x8*)(ap + (kt + 1) * 32);
                acc0 = __builtin_amdgcn_mfma_f32_16x16x32_f16(a0, wgf[kt], acc0, 0, 0, 0);
                acc1 = __builtin_amdgcn_mfma_f32_16x16x32_f16(a1, wgf[kt + 1], acc1, 0, 0, 0);
            }
            f32x4 acc = acc0 + acc1;
            int gc = gcb + wn * 16 + lc;
            #pragma unroll
            for (int q = 0; q < 4; ++q) {
                int br = wm * 16 + lr + q;
                float pre = acc[q] + (float)projrow[(size_t)br * 3072 + gc];
                float sg = 1.f / (1.f + expf(-pre));
                if (gc < NU) {
                    float hv = cloadf(h32d + br * NU + gc);
                    cstore16(rh16d + br * NU + gc, (f16)(sg * hv));
                } else {
                    cstoref(u32d + br * NU + gc - NU, sg);
                }
            }
        }
        ++bc; gbarrier(cnt, bc * 16u);

        // ---- stage rh16d (64KB) coalesced -> LDS stage ----
        #pragma unroll
        for (int qt = 0; qt < 4; ++qt) {
            union { unsigned long long q; f16x4 h; } v[8];
            #pragma unroll
            for (int i = 0; i < 8; ++i)
                v[i].q = cload64(rh16d + (qt * 8 + i) * NU + tid * 4);
            #pragma unroll
            for (int i = 0; i < 8; ++i)
                *(f16x4*)(&stg[(qt * 8 + i) * 1032 + tid * 4]) = v[i].h;
        }
        __syncthreads();

        // ---- phase B: c = tanh(proj_c + (r*h) @ Wc_h); h = u*h + (1-u)*c ----
        if (w < 2) {
            const f16* ap = &stg[(w * 16 + lc) * 1032 + kq];
            const f16* bptr = Wc_lds + lc * 1032 + kq;
            f32x4 acc0 = {}, acc1 = {};
            #pragma unroll
            for (int kt = 0; kt < 32; kt += 2) {
                f16x8 a0 = *(const f16x8*)(ap + kt * 32);
                f16x8 a1 = *(const f16x8*)(ap + (kt + 1) * 32);
                f16x8 b0 = *(const f16x8*)(bptr + kt * 32);
                f16x8 b1 = *(const f16x8*)(bptr + kt * 32 + 32);
                acc0 = __builtin_amdgcn_mfma_f32_16x16x32_f16(a0, b0, acc0, 0, 0, 0);
                acc1 = __builtin_amdgcn_mfma_f32_16x16x32_f16(a1, b1, acc1, 0, 0, 0);
            }
            f32x4 acc = acc0 + acc1;
            int cc = ccb + lc;
            #pragma unroll
            for (int q = 0; q < 4; ++q) {
                int br = w * 16 + lr + q;
                float pre = acc[q] + (float)projrow[(size_t)br * 3072 + 2048 + cc];
                float c = tanhf(pre);
                float u = cloadf(u32d + br * NU + cc);
                float hold = cloadf(h32d + br * NU + cc);
                float hn = u * hold + (1.f - u) * c;
                cstoref(h32d + br * NU + cc, hn);
                cstore16(h16d + br * NU + cc, (f16)hn);
                y[(size_t)(td * NB + br) * 2048 + dir * NU + cc] = (f16)hn;
                if (tl == NT - 1)
                    (dir ? st_bw : st_fw)[br * NU + cc] = hn;
            }
        }
        ++bc; gbarrier(cnt, bc * 16u);
    }
}

// ---------------- host launch ----------------
extern "C" void kernel_launch(void* const* d_in, const int* in_sizes, int n_in,
                              void* d_out, int out_size, void* d_ws, size_t ws_size,
                              hipStream_t stream) {
    const int*   x   = (const int*)  d_in[0];
    const float* emb = (const float*)d_in[1];
    const float* fcW = (const float*)d_in[2];
    const float* fcb = (const float*)d_in[3];
    float* out = (float*)d_out;

    char* ws = (char*)d_ws;
    size_t off = 0;
    f16* seq0   = (f16*)(ws + off); off += (size_t)8192 * 256 * 2;
    f16* ybuf0  = (f16*)(ws + off); off += (size_t)8192 * 2048 * 2;
    f16* ybuf1  = (f16*)(ws + off); off += (size_t)8192 * 2048 * 2;
    f16* projfw = (f16*)(ws + off); off += (size_t)8192 * 3072 * 2;
    f16* projbw = (f16*)(ws + off); off += (size_t)8192 * 3072 * 2;
    float* h32  = (float*)(ws + off); off += 2 * 32 * 1024 * 4;
    f16*   h16  = (f16*)(ws + off);   off += 2 * 32 * 1024 * 2;
    f16*   rh16 = (f16*)(ws + off);   off += 2 * 32 * 1024 * 2;
    float* u32  = (float*)(ws + off); off += 2 * 32 * 1024 * 4;
    unsigned* ctrl = (unsigned*)(ws + off); off += 3 * 1024;

    hipFuncSetAttribute((const void*)gru_layer,
                        hipFuncAttributeMaxDynamicSharedMemorySize, 99072);

    hipMemsetAsync(ctrl, 0, 3 * 1024, stream);
    embed_kernel<<<dim3(8192), dim3(256), 0, stream>>>(x, emb, seq0);

    const f16* lin = seq0; int lda = 256, K = 256;
    f16* ybufs[2] = {ybuf0, ybuf1};
    for (int l = 0; l < 3; ++l) {
        const float* Wg_fw = (const float*)d_in[4 + l * 10 + 0];
        const float* bg_fw = (const float*)d_in[4 + l * 10 + 1];
        const float* Wc_fw = (const float*)d_in[4 + l * 10 + 2];
        const float* bc_fw = (const float*)d_in[4 + l * 10 + 3];
        const float* h0_fw = (const float*)d_in[4 + l * 10 + 4];
        const float* Wg_bw = (const float*)d_in[4 + l * 10 + 5];
        const float* bg_bw = (const float*)d_in[4 + l * 10 + 6];
        const float* Wc_bw = (const float*)d_in[4 + l * 10 + 7];
        const float* bc_bw = (const float*)d_in[4 + l * 10 + 8];
        const float* h0_bw = (const float*)d_in[4 + l * 10 + 9];
        int din = (l == 0) ? 256 : 2048;

        gemm_proj<<<dim3(64, 24), dim3(256), 0, stream>>>(lin, lda, K, Wg_fw, Wc_fw, bg_fw, bc_fw, projfw);
        gemm_proj<<<dim3(64, 24), dim3(256), 0, stream>>>(lin, lda, K, Wg_bw, Wc_bw, bg_bw, bc_bw, projbw);

        const float* Wgh_fw = Wg_fw + (size_t)din * 2048;
        const float* Wgh_bw = Wg_bw + (size_t)din * 2048;
        const float* Wch_fw = Wc_fw + (size_t)din * 1024;
        const float* Wch_bw = Wc_bw + (size_t)din * 1024;
        f16* yout = ybufs[l & 1];
        float* stfw = out + 1048576 + l * 32768;
        float* stbw = out + 1048576 + 98304 + l * 32768;
        const f16* pfw = projfw; const f16* pbw = projbw;
        unsigned* cnt = ctrl + l * 256;

        // PRIMARY: normal launch (no cooperative validation/dispatch path).
        (void)hipGetLastError();  // clear stale error
        gru_layer<<<dim3(128), dim3(256), 99072, stream>>>(
            pfw, pbw, Wgh_fw, Wgh_bw, Wch_fw, Wch_bw, h0_fw, h0_bw,
            h32, h16, rh16, u32, yout, stfw, stbw, cnt);
        if (hipGetLastError() != hipSuccess) {
            // FALLBACK: cooperative launch (r2-proven config for 99072B LDS).
            void* args[] = {
                (void*)&pfw, (void*)&pbw,
                (void*)&Wgh_fw, (void*)&Wgh_bw, (void*)&Wch_fw, (void*)&Wch_bw,
                (void*)&h0_fw, (void*)&h0_bw,
                (void*)&h32, (void*)&h16, (void*)&rh16, (void*)&u32,
                (void*)&yout, (void*)&stfw, (void*)&stbw, (void*)&cnt };
            hipLaunchCooperativeKernel((const void*)gru_layer, dim3(128), dim3(256),
                                       args, (unsigned)99072, stream);
        }
        lin = yout; lda = 2048; K = 2048;
    }

    gemm_fc<<<dim3(64), dim3(256), 0, stream>>>(ybufs[0], fcW, fcb, out);
}

// Round 6
// 9612.411 us; speedup vs baseline: 3.6347x; 1.3937x over previous
//
#include <hip/hip_runtime.h>

typedef _Float16 f16;
typedef _Float16 f16x4 __attribute__((ext_vector_type(4)));
typedef _Float16 f16x8 __attribute__((ext_vector_type(8)));
typedef float f32x4 __attribute__((ext_vector_type(4)));

#define NB 32
#define NT 256
#define NE 256
#define NU 1024
#define NV 128

#define MEMF() asm volatile("" ::: "memory")

// ---------- agent-coherent (cross-XCD, L3-level) load/store helpers ----------
__device__ __forceinline__ unsigned long long cload64(const f16* p) {
    return __hip_atomic_load((const unsigned long long*)p, __ATOMIC_RELAXED,
                             __HIP_MEMORY_SCOPE_AGENT);
}
__device__ __forceinline__ float cloadf(const float* p) {
    return __hip_atomic_load(p, __ATOMIC_RELAXED, __HIP_MEMORY_SCOPE_AGENT);
}
__device__ __forceinline__ void cstoref(float* p, float v) {
    __hip_atomic_store(p, v, __ATOMIC_RELAXED, __HIP_MEMORY_SCOPE_AGENT);
}
__device__ __forceinline__ void cstore16(f16* p, f16 v) {
    __hip_atomic_store((unsigned short*)p, __builtin_bit_cast(unsigned short, v),
                       __ATOMIC_RELAXED, __HIP_MEMORY_SCOPE_AGENT);
}

__device__ __forceinline__ void barsync() {
    MEMF();
    __builtin_amdgcn_s_barrier();
    MEMF();
}

// spin until per-dir counters reach target (threads 0..7 poll, 8 spread counters)
__device__ __forceinline__ void gspin(unsigned* cntd, unsigned target) {
    if (threadIdx.x < 8) {
        int it = 0;
        while (__hip_atomic_load(&cntd[threadIdx.x * 32], __ATOMIC_RELAXED,
                                 __HIP_MEMORY_SCOPE_AGENT) < target) {
            __builtin_amdgcn_s_sleep(1);
            if (++it > (1 << 14)) break;  // failsafe: fail visibly, don't hang
        }
    }
}

// stage 32 rows x 1024 f16 from agent-coherent global into LDS (pitch 1032),
// 16 loads in flight per round, 2 rounds.
__device__ __forceinline__ void stage32(const f16* __restrict__ src,
                                        f16* __restrict__ stg, int tid) {
    #pragma unroll
    for (int rr = 0; rr < 2; ++rr) {
        unsigned long long v[16];
        #pragma unroll
        for (int i = 0; i < 16; ++i)
            v[i] = cload64(src + (rr * 16 + i) * NU + tid * 4);
        MEMF();  // keep all 16 loads issued before the first LDS write
        #pragma unroll
        for (int i = 0; i < 16; ++i)
            *(f16x4*)(&stg[(rr * 16 + i) * 1032 + tid * 4]) =
                __builtin_bit_cast(f16x4, v[i]);
    }
}

// ---------------- embedding ----------------
__global__ void embed_kernel(const int* __restrict__ x, const float* __restrict__ emb,
                             f16* __restrict__ seq0) {
    int row = blockIdx.x;           // t*NB + b
    int t = row >> 5, b = row & 31;
    int e = threadIdx.x;
    int idx = x[b * NT + t];
    seq0[row * NE + e] = (f16)emb[idx * NE + e];
}

// ---------------- input-projection GEMM ----------------
__launch_bounds__(256)
__global__ void gemm_proj(const f16* __restrict__ A, int lda, int K,
                          const float* __restrict__ Wg, const float* __restrict__ Wc,
                          const float* __restrict__ bg, const float* __restrict__ bc,
                          f16* __restrict__ proj) {
    __shared__ f16 As[128][40];
    __shared__ f16 Bs[128][40];
    int cb = blockIdx.y;
    const float* Bsrc; int ldb, outcol; const float* bias;
    if (cb < 16) { Bsrc = Wg + cb * 128; ldb = 2 * NU; outcol = cb * 128; bias = bg + cb * 128; }
    else { Bsrc = Wc + (cb - 16) * 128; ldb = NU; outcol = 2 * NU + (cb - 16) * 128; bias = bc + (cb - 16) * 128; }
    int m0 = blockIdx.x * 128;
    int tid = threadIdx.x;
    int w = tid >> 6, l = tid & 63;
    int wm = w & 1, wn = w >> 1;
    f32x4 acc[4][4] = {};
    for (int k0 = 0; k0 < K; k0 += 32) {
        __syncthreads();
        #pragma unroll
        for (int p = 0; p < 2; ++p) {
            int e = (p * 256 + tid) * 8;
            int r = e >> 5, kq = e & 31;
            f16x8 v = *(const f16x8*)(A + (size_t)(m0 + r) * lda + k0 + kq);
            *(f16x8*)(&As[r][kq]) = v;
        }
        #pragma unroll
        for (int p = 0; p < 4; ++p) {
            int k = p * 8 + (tid >> 5);
            int n = (tid & 31) * 4;
            float4 v = *(const float4*)(Bsrc + (size_t)(k0 + k) * ldb + n);
            Bs[n + 0][k] = (f16)v.x; Bs[n + 1][k] = (f16)v.y;
            Bs[n + 2][k] = (f16)v.z; Bs[n + 3][k] = (f16)v.w;
        }
        __syncthreads();
        int kq = (l >> 4) * 8;
        f16x8 a[4], b[4];
        #pragma unroll
        for (int i = 0; i < 4; ++i) a[i] = *(const f16x8*)(&As[wm * 64 + i * 16 + (l & 15)][kq]);
        #pragma unroll
        for (int j = 0; j < 4; ++j) b[j] = *(const f16x8*)(&Bs[wn * 64 + j * 16 + (l & 15)][kq]);
        #pragma unroll
        for (int i = 0; i < 4; ++i)
            #pragma unroll
            for (int j = 0; j < 4; ++j)
                acc[i][j] = __builtin_amdgcn_mfma_f32_16x16x32_f16(a[i], b[j], acc[i][j], 0, 0, 0);
    }
    int lr = (l >> 4) * 4, lc = l & 15;
    #pragma unroll
    for (int i = 0; i < 4; ++i) {
        #pragma unroll
        for (int j = 0; j < 4; ++j) {
            int gcol = wn * 64 + j * 16 + lc;
            float bia = bias[gcol];
            #pragma unroll
            for (int q = 0; q < 4; ++q) {
                int grow = m0 + wm * 64 + i * 16 + lr + q;
                proj[(size_t)grow * 3072 + outcol + gcol] = (f16)(acc[i][j][q] + bia);
            }
        }
    }
}

// ---------------- final FC ----------------
__launch_bounds__(256)
__global__ void gemm_fc(const f16* __restrict__ y, const float* __restrict__ W,
                        const float* __restrict__ bias, float* __restrict__ out) {
    __shared__ f16 As[128][40];
    __shared__ f16 Bs[128][40];
    int m0 = blockIdx.x * 128;
    int tid = threadIdx.x;
    int w = tid >> 6, l = tid & 63;
    int wm = w & 1, wn = w >> 1;
    f32x4 acc[4][4] = {};
    for (int k0 = 0; k0 < 2048; k0 += 32) {
        __syncthreads();
        #pragma unroll
        for (int p = 0; p < 2; ++p) {
            int e = (p * 256 + tid) * 8;
            int r = e >> 5, kq = e & 31;
            int grow = m0 + r;                 // row = b*256 + t
            int b = grow >> 8, t = grow & 255;
            f16x8 v = *(const f16x8*)(y + (size_t)(t * 32 + b) * 2048 + k0 + kq);
            *(f16x8*)(&As[r][kq]) = v;
        }
        #pragma unroll
        for (int p = 0; p < 4; ++p) {
            int k = p * 8 + (tid >> 5);
            int n = (tid & 31) * 4;
            float4 v = *(const float4*)(W + (size_t)(k0 + k) * 128 + n);
            Bs[n + 0][k] = (f16)v.x; Bs[n + 1][k] = (f16)v.y;
            Bs[n + 2][k] = (f16)v.z; Bs[n + 3][k] = (f16)v.w;
        }
        __syncthreads();
        int kq = (l >> 4) * 8;
        f16x8 a[4], b[4];
        #pragma unroll
        for (int i = 0; i < 4; ++i) a[i] = *(const f16x8*)(&As[wm * 64 + i * 16 + (l & 15)][kq]);
        #pragma unroll
        for (int j = 0; j < 4; ++j) b[j] = *(const f16x8*)(&Bs[wn * 64 + j * 16 + (l & 15)][kq]);
        #pragma unroll
        for (int i = 0; i < 4; ++i)
            #pragma unroll
            for (int j = 0; j < 4; ++j)
                acc[i][j] = __builtin_amdgcn_mfma_f32_16x16x32_f16(a[i], b[j], acc[i][j], 0, 0, 0);
    }
    int lr = (l >> 4) * 4, lc = l & 15;
    #pragma unroll
    for (int i = 0; i < 4; ++i) {
        #pragma unroll
        for (int j = 0; j < 4; ++j) {
            int gcol = wn * 64 + j * 16 + lc;
            float bia = bias[gcol];
            #pragma unroll
            for (int q = 0; q < 4; ++q) {
                int grow = m0 + wm * 64 + i * 16 + lr + q;
                out[(size_t)grow * 128 + gcol] = acc[i][j][q] + bia;
            }
        }
    }
}

// ---------------- recurrent bidirectional GRU layer ----------------
// r5 skeleton, raw-barrier edition. 128 blocks x 256 threads, normal launch.
// LDS: stage[32][1032] f16 + Wc[16][1032] f16 = 99072B. Wg slice in registers.
// Per-direction barriers (64 blocks, 8 spread counters, target 8 each).
// Cand blocks keep their h cells in registers (hreg); h32 eliminated.
__launch_bounds__(256)
__global__ void gru_layer(
    const f16* __restrict__ proj_fw, const f16* __restrict__ proj_bw,
    const float* __restrict__ Wgh_fw, const float* __restrict__ Wgh_bw,
    const float* __restrict__ Wch_fw, const float* __restrict__ Wch_bw,
    const float* __restrict__ h0_fw, const float* __restrict__ h0_bw,
    f16* __restrict__ h16, f16* __restrict__ rh16, float* __restrict__ u32,
    f16* __restrict__ y, float* __restrict__ st_fw, float* __restrict__ st_bw,
    unsigned* __restrict__ cnt)
{
    extern __shared__ f16 smem[];
    f16* stg    = smem;             // [32][1032]
    f16* Wc_lds = smem + 32 * 1032; // [16][1032]

    int bid = blockIdx.x, tid = threadIdx.x;
    int dir = bid >> 6, lb = bid & 63;
    int gcb = lb * 32;   // gate col base (0..2047)
    int ccb = lb * 16;   // cand col base (0..1023)

    const f16*  proj = dir ? proj_bw : proj_fw;
    const float* Wgh = dir ? Wgh_bw : Wgh_fw;
    const float* Wch = dir ? Wch_bw : Wch_fw;
    const float* h0  = dir ? h0_bw  : h0_fw;
    f16*   h16d  = h16  + dir * (NB * NU);
    f16*   rh16d = rh16 + dir * (NB * NU);
    float* u32d  = u32  + dir * (NB * NU);
    unsigned* cntd = cnt + dir * 256;

    int w = tid >> 6, l = tid & 63;
    int lc = l & 15, lr = (l >> 4) * 4, kq = (l >> 4) * 8;
    int wm = w & 1, wn = w >> 1, wb = w & 1;

    // ---- Wc slice into LDS (proven) ----
    {
        int j2 = tid & 15;
        for (int k = tid >> 4; k < NU; k += 16)
            Wc_lds[j2 * 1032 + k] = (f16)Wch[(size_t)k * 1024 + ccb + j2];
    }

    // ---- Wg fragments -> registers (proven) ----
    f16x8 wgf[32];
    {
        int col = gcb + wn * 16 + lc;
        #pragma unroll
        for (int kt = 0; kt < 32; ++kt) {
            f16x8 t;
            #pragma unroll
            for (int e = 0; e < 8; ++e)
                t[e] = (f16)Wgh[(size_t)(kt * 32 + kq + e) * 2048 + col];
            wgf[kt] = t;
        }
    }

    // ---- init h: publish h16 (all blocks, disjoint slices); cand h in regs ----
    {
        int base = lb * 512;
        for (int i = tid; i < 512; i += 256)
            cstore16(h16d + base + i, (f16)h0[base + i]);
    }
    f32x4 hreg = {};
    if (w < 2) {
        #pragma unroll
        for (int q = 0; q < 4; ++q)
            hreg[q] = h0[(size_t)(wb * 16 + lr + q) * NU + ccb + lc];
    }

    unsigned bc = 1;
    // barrier: drain stores, block-sync, add, spin, block-sync
    asm volatile("s_waitcnt vmcnt(0)" ::: "memory");
    barsync();
    if (tid == 0)
        __hip_atomic_fetch_add(&cntd[(bid & 7) * 32], 1u,
                               __ATOMIC_RELAXED, __HIP_MEMORY_SCOPE_AGENT);
    gspin(cntd, bc * 8u);
    barsync();

    for (int tl = 0; tl < NT; ++tl) {
        int td = dir ? (NT - 1 - tl) : tl;
        const f16* projrow = proj + (size_t)td * NB * 3072;

        // ---- prefetch this step's proj operands (plain loads, stay in flight) ----
        f16 pg[4], pc[4];
        {
            int gc = gcb + wn * 16 + lc;
            int cc2 = 2048 + ccb + lc;
            #pragma unroll
            for (int q = 0; q < 4; ++q) {
                pg[q] = projrow[(size_t)(wm * 16 + lr + q) * 3072 + gc];
                pc[q] = projrow[(size_t)(wb * 16 + lr + q) * 3072 + cc2];
            }
        }

        // ---- stage h16 -> LDS ----
        stage32(h16d, stg, tid);
        asm volatile("s_waitcnt lgkmcnt(0)" ::: "memory");
        __builtin_amdgcn_sched_barrier(0);
        barsync();

        // ---- phase A: ru = sigmoid(proj_g + h @ Wg_h) ----
        {
            const f16* ap = &stg[(wm * 16 + lc) * 1032 + kq];
            f32x4 acc0 = {}, acc1 = {};
            #pragma unroll
            for (int kt = 0; kt < 32; kt += 2) {
                f16x8 a0 = *(const f16x8*)(ap + kt * 32);
                f16x8 a1 = *(const f16x8*)(ap + (kt + 1) * 32);
                acc0 = __builtin_amdgcn_mfma_f32_16x16x32_f16(a0, wgf[kt], acc0, 0, 0, 0);
                acc1 = __builtin_amdgcn_mfma_f32_16x16x32_f16(a1, wgf[kt + 1], acc1, 0, 0, 0);
            }
            f32x4 acc = acc0 + acc1;
            int gc = gcb + wn * 16 + lc;
            #pragma unroll
            for (int q = 0; q < 4; ++q) {
                int br = wm * 16 + lr + q;
                float pre = acc[q] + (float)pg[q];
                float sg = 1.f / (1.f + __expf(-pre));
                if (gc < NU) {   // r-block (block-uniform): rh from staged h16
                    float hv = (float)stg[br * 1032 + gc];
                    cstore16(rh16d + br * NU + gc, (f16)(sg * hv));
                } else {         // u-block
                    cstoref(u32d + br * NU + gc - NU, sg);
                }
            }
        }
        ++bc;
        asm volatile("s_waitcnt vmcnt(0)" ::: "memory");  // rh/u at L3
        barsync();
        if (tid == 0)
            __hip_atomic_fetch_add(&cntd[(bid & 7) * 32], 1u,
                                   __ATOMIC_RELAXED, __HIP_MEMORY_SCOPE_AGENT);
        gspin(cntd, bc * 8u);
        barsync();

        // ---- stage rh16 -> LDS ----
        stage32(rh16d, stg, tid);
        asm volatile("s_waitcnt lgkmcnt(0)" ::: "memory");
        __builtin_amdgcn_sched_barrier(0);
        barsync();

        // ---- phase B: c = tanh(proj_c + (r*h) @ Wc_h); h = u*h + (1-u)*c ----
        int cc = ccb + lc;
        if (w < 2) {
            const f16* ap = &stg[(wb * 16 + lc) * 1032 + kq];
            const f16* bptr = Wc_lds + lc * 1032 + kq;
            f32x4 acc0 = {}, acc1 = {};
            #pragma unroll
            for (int kt = 0; kt < 32; kt += 2) {
                f16x8 a0 = *(const f16x8*)(ap + kt * 32);
                f16x8 a1 = *(const f16x8*)(ap + (kt + 1) * 32);
                f16x8 b0 = *(const f16x8*)(bptr + kt * 32);
                f16x8 b1 = *(const f16x8*)(bptr + kt * 32 + 32);
                acc0 = __builtin_amdgcn_mfma_f32_16x16x32_f16(a0, b0, acc0, 0, 0, 0);
                acc1 = __builtin_amdgcn_mfma_f32_16x16x32_f16(a1, b1, acc1, 0, 0, 0);
            }
            f32x4 acc = acc0 + acc1;
            #pragma unroll
            for (int q = 0; q < 4; ++q) {
                int br = wb * 16 + lr + q;
                float pre = acc[q] + (float)pc[q];
                float c = tanhf(pre);
                float u = cloadf(u32d + br * NU + cc);
                float hn = u * hreg[q] + (1.f - u) * c;
                hreg[q] = hn;
                cstore16(h16d + br * NU + cc, (f16)hn);
            }
        }
        ++bc;
        asm volatile("s_waitcnt vmcnt(0)" ::: "memory");  // h16 at L3
        // y / final-state stores go AFTER the drain: not needed by other blocks
        if (w < 2) {
            #pragma unroll
            for (int q = 0; q < 4; ++q) {
                int br = wb * 16 + lr + q;
                y[(size_t)(td * NB + br) * 2048 + dir * NU + cc] = (f16)hreg[q];
                if (tl == NT - 1)
                    (dir ? st_bw : st_fw)[br * NU + cc] = hreg[q];
            }
        }
        barsync();
        if (tid == 0)
            __hip_atomic_fetch_add(&cntd[(bid & 7) * 32], 1u,
                                   __ATOMIC_RELAXED, __HIP_MEMORY_SCOPE_AGENT);
        gspin(cntd, bc * 8u);
        barsync();
    }
}

// ---------------- host launch ----------------
extern "C" void kernel_launch(void* const* d_in, const int* in_sizes, int n_in,
                              void* d_out, int out_size, void* d_ws, size_t ws_size,
                              hipStream_t stream) {
    const int*   x   = (const int*)  d_in[0];
    const float* emb = (const float*)d_in[1];
    const float* fcW = (const float*)d_in[2];
    const float* fcb = (const float*)d_in[3];
    float* out = (float*)d_out;

    char* ws = (char*)d_ws;
    size_t off = 0;
    f16* seq0   = (f16*)(ws + off); off += (size_t)8192 * 256 * 2;
    f16* ybuf0  = (f16*)(ws + off); off += (size_t)8192 * 2048 * 2;
    f16* ybuf1  = (f16*)(ws + off); off += (size_t)8192 * 2048 * 2;
    f16* projfw = (f16*)(ws + off); off += (size_t)8192 * 3072 * 2;
    f16* projbw = (f16*)(ws + off); off += (size_t)8192 * 3072 * 2;
    f16*   h16  = (f16*)(ws + off);   off += 2 * 32 * 1024 * 2;
    f16*   rh16 = (f16*)(ws + off);   off += 2 * 32 * 1024 * 2;
    float* u32  = (float*)(ws + off); off += 2 * 32 * 1024 * 4;
    unsigned* ctrl = (unsigned*)(ws + off); off += 3 * 2048;

    hipFuncSetAttribute((const void*)gru_layer,
                        hipFuncAttributeMaxDynamicSharedMemorySize, 99072);

    hipMemsetAsync(ctrl, 0, 3 * 2048, stream);
    embed_kernel<<<dim3(8192), dim3(256), 0, stream>>>(x, emb, seq0);

    const f16* lin = seq0; int lda = 256, K = 256;
    f16* ybufs[2] = {ybuf0, ybuf1};
    for (int l = 0; l < 3; ++l) {
        const float* Wg_fw = (const float*)d_in[4 + l * 10 + 0];
        const float* bg_fw = (const float*)d_in[4 + l * 10 + 1];
        const float* Wc_fw = (const float*)d_in[4 + l * 10 + 2];
        const float* bc_fw = (const float*)d_in[4 + l * 10 + 3];
        const float* h0_fw = (const float*)d_in[4 + l * 10 + 4];
        const float* Wg_bw = (const float*)d_in[4 + l * 10 + 5];
        const float* bg_bw = (const float*)d_in[4 + l * 10 + 6];
        const float* Wc_bw = (const float*)d_in[4 + l * 10 + 7];
        const float* bc_bw = (const float*)d_in[4 + l * 10 + 8];
        const float* h0_bw = (const float*)d_in[4 + l * 10 + 9];
        int din = (l == 0) ? 256 : 2048;

        gemm_proj<<<dim3(64, 24), dim3(256), 0, stream>>>(lin, lda, K, Wg_fw, Wc_fw, bg_fw, bc_fw, projfw);
        gemm_proj<<<dim3(64, 24), dim3(256), 0, stream>>>(lin, lda, K, Wg_bw, Wc_bw, bg_bw, bc_bw, projbw);

        const float* Wgh_fw = Wg_fw + (size_t)din * 2048;
        const float* Wgh_bw = Wg_bw + (size_t)din * 2048;
        const float* Wch_fw = Wc_fw + (size_t)din * 1024;
        const float* Wch_bw = Wc_bw + (size_t)din * 1024;
        f16* yout = ybufs[l & 1];
        float* stfw = out + 1048576 + l * 32768;
        float* stbw = out + 1048576 + 98304 + l * 32768;
        unsigned* cnt = ctrl + l * 512;

        gru_layer<<<dim3(128), dim3(256), 99072, stream>>>(
            projfw, projbw, Wgh_fw, Wgh_bw, Wch_fw, Wch_bw, h0_fw, h0_bw,
            h16, rh16, u32, yout, stfw, stbw, cnt);
        lin = yout; lda = 2048; K = 2048;
    }

    gemm_fc<<<dim3(64), dim3(256), 0, stream>>>(ybufs[0], fcW, fcb, out);
}

// Round 7
// 8116.424 us; speedup vs baseline: 4.3046x; 1.1843x over previous
//
#include <hip/hip_runtime.h>

typedef _Float16 f16;
typedef _Float16 f16x4 __attribute__((ext_vector_type(4)));
typedef _Float16 f16x8 __attribute__((ext_vector_type(8)));
typedef float f32x4 __attribute__((ext_vector_type(4)));

#define NB 32
#define NT 256
#define NE 256
#define NU 1024
#define NV 128

#define MEMF() asm volatile("" ::: "memory")

// ---------- agent-coherent (cross-XCD, L3-level) load/store helpers ----------
__device__ __forceinline__ unsigned long long cload64(const f16* p) {
    return __hip_atomic_load((const unsigned long long*)p, __ATOMIC_RELAXED,
                             __HIP_MEMORY_SCOPE_AGENT);
}
__device__ __forceinline__ float cloadf(const float* p) {
    return __hip_atomic_load(p, __ATOMIC_RELAXED, __HIP_MEMORY_SCOPE_AGENT);
}
__device__ __forceinline__ void cstoref(float* p, float v) {
    __hip_atomic_store(p, v, __ATOMIC_RELAXED, __HIP_MEMORY_SCOPE_AGENT);
}
__device__ __forceinline__ void cstore16(f16* p, f16 v) {
    __hip_atomic_store((unsigned short*)p, __builtin_bit_cast(unsigned short, v),
                       __ATOMIC_RELAXED, __HIP_MEMORY_SCOPE_AGENT);
}

__device__ __forceinline__ void barsync() {
    MEMF();
    __builtin_amdgcn_s_barrier();
    MEMF();
}

// spin until per-dir counters reach target (threads 0..7 poll, 8 spread counters)
__device__ __forceinline__ void gspin(unsigned* cntd, unsigned target) {
    if (threadIdx.x < 8) {
        int it = 0;
        while (__hip_atomic_load(&cntd[threadIdx.x * 32], __ATOMIC_RELAXED,
                                 __HIP_MEMORY_SCOPE_AGENT) < target) {
            __builtin_amdgcn_s_sleep(1);
            if (++it > (1 << 14)) break;  // failsafe: fail visibly, don't hang
        }
    }
}

// stage 32 rows x 1024 f16 from agent-coherent global into LDS (pitch 1032).
// All 32 loads issued before any LDS write -> ONE L3 round trip (r6 had two).
__device__ __forceinline__ void stage32(const f16* __restrict__ src,
                                        f16* __restrict__ stg, int tid) {
    unsigned long long a[16], b[16];
    #pragma unroll
    for (int i = 0; i < 16; ++i)
        a[i] = cload64(src + i * NU + tid * 4);
    MEMF();
    #pragma unroll
    for (int i = 0; i < 16; ++i)
        b[i] = cload64(src + (16 + i) * NU + tid * 4);
    MEMF();
    #pragma unroll
    for (int i = 0; i < 16; ++i)
        *(f16x4*)(&stg[i * 1032 + tid * 4]) = __builtin_bit_cast(f16x4, a[i]);
    #pragma unroll
    for (int i = 0; i < 16; ++i)
        *(f16x4*)(&stg[(16 + i) * 1032 + tid * 4]) = __builtin_bit_cast(f16x4, b[i]);
}

// ---------------- embedding ----------------
__global__ void embed_kernel(const int* __restrict__ x, const float* __restrict__ emb,
                             f16* __restrict__ seq0) {
    int row = blockIdx.x;           // t*NB + b
    int t = row >> 5, b = row & 31;
    int e = threadIdx.x;
    int idx = x[b * NT + t];
    seq0[row * NE + e] = (f16)emb[idx * NE + e];
}

// ---------------- weight transpose+convert: WT[n][k] (f16) = W[k][n] (f32) ----------------
// blockIdx.z: 0=Wg (N=2048), 1=Wc (N=1024). K2 % 32 == 0.
__global__ void wconv(const float* __restrict__ Wg, const float* __restrict__ Wc,
                      f16* __restrict__ WgT, f16* __restrict__ WcT, int K2) {
    __shared__ float tile[32][33];
    int mat = blockIdx.z & 1;
    const float* in = mat ? Wc : Wg;
    f16* outp = mat ? WcT : WgT;
    int N = mat ? 1024 : 2048;
    int by = blockIdx.y;
    if (by * 32 >= N) return;
    int k0 = blockIdx.x * 32, n0 = by * 32;
    int tx = threadIdx.x & 31, ty = threadIdx.x >> 5;  // 32 x 8
    #pragma unroll
    for (int i = 0; i < 4; ++i) {
        int r = ty * 4 + i;
        tile[r][tx] = in[(size_t)(k0 + r) * N + n0 + tx];
    }
    __syncthreads();
    #pragma unroll
    for (int i = 0; i < 4; ++i) {
        int rn = ty * 4 + i;
        outp[(size_t)(n0 + rn) * K2 + k0 + tx] = (f16)tile[tx][rn];
    }
}

// ---------------- input-projection GEMM, f16 transposed-weight edition ----------------
__launch_bounds__(256)
__global__ void gemm_projT(const f16* __restrict__ A, int lda, int K,
                           const f16* __restrict__ WgT, const f16* __restrict__ WcT, int K2,
                           const float* __restrict__ bg, const float* __restrict__ bc,
                           f16* __restrict__ proj) {
    __shared__ f16 As[128][40];
    __shared__ f16 Bs[128][40];
    int cb = blockIdx.y;
    const f16* Bsrc; int outcol; const float* bias;
    if (cb < 16) { Bsrc = WgT + (size_t)cb * 128 * K2; outcol = cb * 128; bias = bg + cb * 128; }
    else { Bsrc = WcT + (size_t)(cb - 16) * 128 * K2; outcol = 2048 + (cb - 16) * 128; bias = bc + (cb - 16) * 128; }
    int m0 = blockIdx.x * 128;
    int tid = threadIdx.x;
    int w = tid >> 6, l = tid & 63;
    int wm = w & 1, wn = w >> 1;
    f32x4 acc[4][4] = {};
    for (int k0 = 0; k0 < K; k0 += 32) {
        __syncthreads();
        #pragma unroll
        for (int p = 0; p < 2; ++p) {
            int e = (p * 256 + tid) * 8;
            int r = e >> 5, kq = e & 31;
            f16x8 v = *(const f16x8*)(A + (size_t)(m0 + r) * lda + k0 + kq);
            *(f16x8*)(&As[r][kq]) = v;
        }
        #pragma unroll
        for (int p = 0; p < 2; ++p) {
            int e = (p * 256 + tid) * 8;
            int r = e >> 5, kq = e & 31;
            f16x8 v = *(const f16x8*)(Bsrc + (size_t)r * K2 + k0 + kq);
            *(f16x8*)(&Bs[r][kq]) = v;
        }
        __syncthreads();
        int kq = (l >> 4) * 8;
        f16x8 a[4], b[4];
        #pragma unroll
        for (int i = 0; i < 4; ++i) a[i] = *(const f16x8*)(&As[wm * 64 + i * 16 + (l & 15)][kq]);
        #pragma unroll
        for (int j = 0; j < 4; ++j) b[j] = *(const f16x8*)(&Bs[wn * 64 + j * 16 + (l & 15)][kq]);
        #pragma unroll
        for (int i = 0; i < 4; ++i)
            #pragma unroll
            for (int j = 0; j < 4; ++j)
                acc[i][j] = __builtin_amdgcn_mfma_f32_16x16x32_f16(a[i], b[j], acc[i][j], 0, 0, 0);
    }
    int lr = (l >> 4) * 4, lc = l & 15;
    #pragma unroll
    for (int i = 0; i < 4; ++i) {
        #pragma unroll
        for (int j = 0; j < 4; ++j) {
            int gcol = wn * 64 + j * 16 + lc;
            float bia = bias[gcol];
            #pragma unroll
            for (int q = 0; q < 4; ++q) {
                int grow = m0 + wm * 64 + i * 16 + lr + q;
                proj[(size_t)grow * 3072 + outcol + gcol] = (f16)(acc[i][j][q] + bia);
            }
        }
    }
}

// ---------------- input-projection GEMM (r6 fallback, f32 weights) ----------------
__launch_bounds__(256)
__global__ void gemm_proj(const f16* __restrict__ A, int lda, int K,
                          const float* __restrict__ Wg, const float* __restrict__ Wc,
                          const float* __restrict__ bg, const float* __restrict__ bc,
                          f16* __restrict__ proj) {
    __shared__ f16 As[128][40];
    __shared__ f16 Bs[128][40];
    int cb = blockIdx.y;
    const float* Bsrc; int ldb, outcol; const float* bias;
    if (cb < 16) { Bsrc = Wg + cb * 128; ldb = 2 * NU; outcol = cb * 128; bias = bg + cb * 128; }
    else { Bsrc = Wc + (cb - 16) * 128; ldb = NU; outcol = 2 * NU + (cb - 16) * 128; bias = bc + (cb - 16) * 128; }
    int m0 = blockIdx.x * 128;
    int tid = threadIdx.x;
    int w = tid >> 6, l = tid & 63;
    int wm = w & 1, wn = w >> 1;
    f32x4 acc[4][4] = {};
    for (int k0 = 0; k0 < K; k0 += 32) {
        __syncthreads();
        #pragma unroll
        for (int p = 0; p < 2; ++p) {
            int e = (p * 256 + tid) * 8;
            int r = e >> 5, kq = e & 31;
            f16x8 v = *(const f16x8*)(A + (size_t)(m0 + r) * lda + k0 + kq);
            *(f16x8*)(&As[r][kq]) = v;
        }
        #pragma unroll
        for (int p = 0; p < 4; ++p) {
            int k = p * 8 + (tid >> 5);
            int n = (tid & 31) * 4;
            float4 v = *(const float4*)(Bsrc + (size_t)(k0 + k) * ldb + n);
            Bs[n + 0][k] = (f16)v.x; Bs[n + 1][k] = (f16)v.y;
            Bs[n + 2][k] = (f16)v.z; Bs[n + 3][k] = (f16)v.w;
        }
        __syncthreads();
        int kq = (l >> 4) * 8;
        f16x8 a[4], b[4];
        #pragma unroll
        for (int i = 0; i < 4; ++i) a[i] = *(const f16x8*)(&As[wm * 64 + i * 16 + (l & 15)][kq]);
        #pragma unroll
        for (int j = 0; j < 4; ++j) b[j] = *(const f16x8*)(&Bs[wn * 64 + j * 16 + (l & 15)][kq]);
        #pragma unroll
        for (int i = 0; i < 4; ++i)
            #pragma unroll
            for (int j = 0; j < 4; ++j)
                acc[i][j] = __builtin_amdgcn_mfma_f32_16x16x32_f16(a[i], b[j], acc[i][j], 0, 0, 0);
    }
    int lr = (l >> 4) * 4, lc = l & 15;
    #pragma unroll
    for (int i = 0; i < 4; ++i) {
        #pragma unroll
        for (int j = 0; j < 4; ++j) {
            int gcol = wn * 64 + j * 16 + lc;
            float bia = bias[gcol];
            #pragma unroll
            for (int q = 0; q < 4; ++q) {
                int grow = m0 + wm * 64 + i * 16 + lr + q;
                proj[(size_t)grow * 3072 + outcol + gcol] = (f16)(acc[i][j][q] + bia);
            }
        }
    }
}

// ---------------- final FC ----------------
__launch_bounds__(256)
__global__ void gemm_fc(const f16* __restrict__ y, const float* __restrict__ W,
                        const float* __restrict__ bias, float* __restrict__ out) {
    __shared__ f16 As[128][40];
    __shared__ f16 Bs[128][40];
    int m0 = blockIdx.x * 128;
    int tid = threadIdx.x;
    int w = tid >> 6, l = tid & 63;
    int wm = w & 1, wn = w >> 1;
    f32x4 acc[4][4] = {};
    for (int k0 = 0; k0 < 2048; k0 += 32) {
        __syncthreads();
        #pragma unroll
        for (int p = 0; p < 2; ++p) {
            int e = (p * 256 + tid) * 8;
            int r = e >> 5, kq = e & 31;
            int grow = m0 + r;                 // row = b*256 + t
            int b = grow >> 8, t = grow & 255;
            f16x8 v = *(const f16x8*)(y + (size_t)(t * 32 + b) * 2048 + k0 + kq);
            *(f16x8*)(&As[r][kq]) = v;
        }
        #pragma unroll
        for (int p = 0; p < 4; ++p) {
            int k = p * 8 + (tid >> 5);
            int n = (tid & 31) * 4;
            float4 v = *(const float4*)(W + (size_t)(k0 + k) * 128 + n);
            Bs[n + 0][k] = (f16)v.x; Bs[n + 1][k] = (f16)v.y;
            Bs[n + 2][k] = (f16)v.z; Bs[n + 3][k] = (f16)v.w;
        }
        __syncthreads();
        int kq = (l >> 4) * 8;
        f16x8 a[4], b[4];
        #pragma unroll
        for (int i = 0; i < 4; ++i) a[i] = *(const f16x8*)(&As[wm * 64 + i * 16 + (l & 15)][kq]);
        #pragma unroll
        for (int j = 0; j < 4; ++j) b[j] = *(const f16x8*)(&Bs[wn * 64 + j * 16 + (l & 15)][kq]);
        #pragma unroll
        for (int i = 0; i < 4; ++i)
            #pragma unroll
            for (int j = 0; j < 4; ++j)
                acc[i][j] = __builtin_amdgcn_mfma_f32_16x16x32_f16(a[i], b[j], acc[i][j], 0, 0, 0);
    }
    int lr = (l >> 4) * 4, lc = l & 15;
    #pragma unroll
    for (int i = 0; i < 4; ++i) {
        #pragma unroll
        for (int j = 0; j < 4; ++j) {
            int gcol = wn * 64 + j * 16 + lc;
            float bia = bias[gcol];
            #pragma unroll
            for (int q = 0; q < 4; ++q) {
                int grow = m0 + wm * 64 + i * 16 + lr + q;
                out[(size_t)grow * 128 + gcol] = acc[i][j][q] + bia;
            }
        }
    }
}

// ---------------- recurrent bidirectional GRU layer (r6-verbatim except stage32) ----------
__launch_bounds__(256)
__global__ void gru_layer(
    const f16* __restrict__ proj_fw, const f16* __restrict__ proj_bw,
    const float* __restrict__ Wgh_fw, const float* __restrict__ Wgh_bw,
    const float* __restrict__ Wch_fw, const float* __restrict__ Wch_bw,
    const float* __restrict__ h0_fw, const float* __restrict__ h0_bw,
    f16* __restrict__ h16, f16* __restrict__ rh16, float* __restrict__ u32,
    f16* __restrict__ y, float* __restrict__ st_fw, float* __restrict__ st_bw,
    unsigned* __restrict__ cnt)
{
    extern __shared__ f16 smem[];
    f16* stg    = smem;             // [32][1032]
    f16* Wc_lds = smem + 32 * 1032; // [16][1032]

    int bid = blockIdx.x, tid = threadIdx.x;
    int dir = bid >> 6, lb = bid & 63;
    int gcb = lb * 32;   // gate col base (0..2047)
    int ccb = lb * 16;   // cand col base (0..1023)

    const f16*  proj = dir ? proj_bw : proj_fw;
    const float* Wgh = dir ? Wgh_bw : Wgh_fw;
    const float* Wch = dir ? Wch_bw : Wch_fw;
    const float* h0  = dir ? h0_bw  : h0_fw;
    f16*   h16d  = h16  + dir * (NB * NU);
    f16*   rh16d = rh16 + dir * (NB * NU);
    float* u32d  = u32  + dir * (NB * NU);
    unsigned* cntd = cnt + dir * 256;

    int w = tid >> 6, l = tid & 63;
    int lc = l & 15, lr = (l >> 4) * 4, kq = (l >> 4) * 8;
    int wm = w & 1, wn = w >> 1, wb = w & 1;

    // ---- Wc slice into LDS (proven) ----
    {
        int j2 = tid & 15;
        for (int k = tid >> 4; k < NU; k += 16)
            Wc_lds[j2 * 1032 + k] = (f16)Wch[(size_t)k * 1024 + ccb + j2];
    }

    // ---- Wg fragments -> registers (proven) ----
    f16x8 wgf[32];
    {
        int col = gcb + wn * 16 + lc;
        #pragma unroll
        for (int kt = 0; kt < 32; ++kt) {
            f16x8 t;
            #pragma unroll
            for (int e = 0; e < 8; ++e)
                t[e] = (f16)Wgh[(size_t)(kt * 32 + kq + e) * 2048 + col];
            wgf[kt] = t;
        }
    }

    // ---- init h: publish h16 (all blocks, disjoint slices); cand h in regs ----
    {
        int base = lb * 512;
        for (int i = tid; i < 512; i += 256)
            cstore16(h16d + base + i, (f16)h0[base + i]);
    }
    f32x4 hreg = {};
    if (w < 2) {
        #pragma unroll
        for (int q = 0; q < 4; ++q)
            hreg[q] = h0[(size_t)(wb * 16 + lr + q) * NU + ccb + lc];
    }

    unsigned bc = 1;
    asm volatile("s_waitcnt vmcnt(0)" ::: "memory");
    barsync();
    if (tid == 0)
        __hip_atomic_fetch_add(&cntd[(bid & 7) * 32], 1u,
                               __ATOMIC_RELAXED, __HIP_MEMORY_SCOPE_AGENT);
    gspin(cntd, bc * 8u);
    barsync();

    for (int tl = 0; tl < NT; ++tl) {
        int td = dir ? (NT - 1 - tl) : tl;
        const f16* projrow = proj + (size_t)td * NB * 3072;

        // ---- prefetch this step's proj operands ----
        f16 pg[4], pc[4];
        {
            int gc = gcb + wn * 16 + lc;
            int cc2 = 2048 + ccb + lc;
            #pragma unroll
            for (int q = 0; q < 4; ++q) {
                pg[q] = projrow[(size_t)(wm * 16 + lr + q) * 3072 + gc];
                pc[q] = projrow[(size_t)(wb * 16 + lr + q) * 3072 + cc2];
            }
        }

        // ---- stage h16 -> LDS ----
        stage32(h16d, stg, tid);
        asm volatile("s_waitcnt lgkmcnt(0)" ::: "memory");
        __builtin_amdgcn_sched_barrier(0);
        barsync();

        // ---- phase A: ru = sigmoid(proj_g + h @ Wg_h) ----
        {
            const f16* ap = &stg[(wm * 16 + lc) * 1032 + kq];
            f32x4 acc0 = {}, acc1 = {};
            #pragma unroll
            for (int kt = 0; kt < 32; kt += 2) {
                f16x8 a0 = *(const f16x8*)(ap + kt * 32);
                f16x8 a1 = *(const f16x8*)(ap + (kt + 1) * 32);
                acc0 = __builtin_amdgcn_mfma_f32_16x16x32_f16(a0, wgf[kt], acc0, 0, 0, 0);
                acc1 = __builtin_amdgcn_mfma_f32_16x16x32_f16(a1, wgf[kt + 1], acc1, 0, 0, 0);
            }
            f32x4 acc = acc0 + acc1;
            int gc = gcb + wn * 16 + lc;
            #pragma unroll
            for (int q = 0; q < 4; ++q) {
                int br = wm * 16 + lr + q;
                float pre = acc[q] + (float)pg[q];
                float sg = 1.f / (1.f + __expf(-pre));
                if (gc < NU) {   // r-block (block-uniform): rh from staged h16
                    float hv = (float)stg[br * 1032 + gc];
                    cstore16(rh16d + br * NU + gc, (f16)(sg * hv));
                } else {         // u-block
                    cstoref(u32d + br * NU + gc - NU, sg);
                }
            }
        }
        ++bc;
        asm volatile("s_waitcnt vmcnt(0)" ::: "memory");  // rh/u at L3
        barsync();
        if (tid == 0)
            __hip_atomic_fetch_add(&cntd[(bid & 7) * 32], 1u,
                                   __ATOMIC_RELAXED, __HIP_MEMORY_SCOPE_AGENT);
        gspin(cntd, bc * 8u);
        barsync();

        // ---- stage rh16 -> LDS ----
        stage32(rh16d, stg, tid);
        asm volatile("s_waitcnt lgkmcnt(0)" ::: "memory");
        __builtin_amdgcn_sched_barrier(0);
        barsync();

        // ---- phase B: c = tanh(proj_c + (r*h) @ Wc_h); h = u*h + (1-u)*c ----
        int cc = ccb + lc;
        if (w < 2) {
            const f16* ap = &stg[(wb * 16 + lc) * 1032 + kq];
            const f16* bptr = Wc_lds + lc * 1032 + kq;
            f32x4 acc0 = {}, acc1 = {};
            #pragma unroll
            for (int kt = 0; kt < 32; kt += 2) {
                f16x8 a0 = *(const f16x8*)(ap + kt * 32);
                f16x8 a1 = *(const f16x8*)(ap + (kt + 1) * 32);
                f16x8 b0 = *(const f16x8*)(bptr + kt * 32);
                f16x8 b1 = *(const f16x8*)(bptr + kt * 32 + 32);
                acc0 = __builtin_amdgcn_mfma_f32_16x16x32_f16(a0, b0, acc0, 0, 0, 0);
                acc1 = __builtin_amdgcn_mfma_f32_16x16x32_f16(a1, b1, acc1, 0, 0, 0);
            }
            f32x4 acc = acc0 + acc1;
            #pragma unroll
            for (int q = 0; q < 4; ++q) {
                int br = wb * 16 + lr + q;
                float pre = acc[q] + (float)pc[q];
                float c = tanhf(pre);
                float u = cloadf(u32d + br * NU + cc);
                float hn = u * hreg[q] + (1.f - u) * c;
                hreg[q] = hn;
                cstore16(h16d + br * NU + cc, (f16)hn);
            }
        }
        ++bc;
        asm volatile("s_waitcnt vmcnt(0)" ::: "memory");  // h16 at L3
        if (w < 2) {
            #pragma unroll
            for (int q = 0; q < 4; ++q) {
                int br = wb * 16 + lr + q;
                y[(size_t)(td * NB + br) * 2048 + dir * NU + cc] = (f16)hreg[q];
                if (tl == NT - 1)
                    (dir ? st_bw : st_fw)[br * NU + cc] = hreg[q];
            }
        }
        barsync();
        if (tid == 0)
            __hip_atomic_fetch_add(&cntd[(bid & 7) * 32], 1u,
                                   __ATOMIC_RELAXED, __HIP_MEMORY_SCOPE_AGENT);
        gspin(cntd, bc * 8u);
        barsync();
    }
}

// ---------------- host launch ----------------
extern "C" void kernel_launch(void* const* d_in, const int* in_sizes, int n_in,
                              void* d_out, int out_size, void* d_ws, size_t ws_size,
                              hipStream_t stream) {
    const int*   x   = (const int*)  d_in[0];
    const float* emb = (const float*)d_in[1];
    const float* fcW = (const float*)d_in[2];
    const float* fcb = (const float*)d_in[3];
    float* out = (float*)d_out;

    char* ws = (char*)d_ws;
    size_t off = 0;
    f16* seq0   = (f16*)(ws + off); off += (size_t)8192 * 256 * 2;
    f16* ybuf0  = (f16*)(ws + off); off += (size_t)8192 * 2048 * 2;
    f16* ybuf1  = (f16*)(ws + off); off += (size_t)8192 * 2048 * 2;
    f16* projfw = (f16*)(ws + off); off += (size_t)8192 * 3072 * 2;
    f16* projbw = (f16*)(ws + off); off += (size_t)8192 * 3072 * 2;
    f16*   h16  = (f16*)(ws + off);   off += 2 * 32 * 1024 * 2;
    f16*   rh16 = (f16*)(ws + off);   off += 2 * 32 * 1024 * 2;
    float* u32  = (float*)(ws + off); off += 2 * 32 * 1024 * 4;
    unsigned* ctrl = (unsigned*)(ws + off); off += 3 * 2048;
    // per-layer-reused f16 transposed-weight slot (max-layer sizes, K2=3072)
    f16* WgT_fw = (f16*)(ws + off); off += (size_t)2048 * 3072 * 2;
    f16* WgT_bw = (f16*)(ws + off); off += (size_t)2048 * 3072 * 2;
    f16* WcT_fw = (f16*)(ws + off); off += (size_t)1024 * 3072 * 2;
    f16* WcT_bw = (f16*)(ws + off); off += (size_t)1024 * 3072 * 2;
    bool cvt = (ws_size >= off);   // fall back to f32 gemm if slot doesn't fit

    hipFuncSetAttribute((const void*)gru_layer,
                        hipFuncAttributeMaxDynamicSharedMemorySize, 99072);

    hipMemsetAsync(ctrl, 0, 3 * 2048, stream);
    embed_kernel<<<dim3(8192), dim3(256), 0, stream>>>(x, emb, seq0);

    const f16* lin = seq0; int lda = 256, K = 256;
    f16* ybufs[2] = {ybuf0, ybuf1};
    for (int l = 0; l < 3; ++l) {
        const float* Wg_fw = (const float*)d_in[4 + l * 10 + 0];
        const float* bg_fw = (const float*)d_in[4 + l * 10 + 1];
        const float* Wc_fw = (const float*)d_in[4 + l * 10 + 2];
        const float* bc_fw = (const float*)d_in[4 + l * 10 + 3];
        const float* h0_fw = (const float*)d_in[4 + l * 10 + 4];
        const float* Wg_bw = (const float*)d_in[4 + l * 10 + 5];
        const float* bg_bw = (const float*)d_in[4 + l * 10 + 6];
        const float* Wc_bw = (const float*)d_in[4 + l * 10 + 7];
        const float* bc_bw = (const float*)d_in[4 + l * 10 + 8];
        const float* h0_bw = (const float*)d_in[4 + l * 10 + 9];
        int din = (l == 0) ? 256 : 2048;
        int K2 = din + 1024;

        if (cvt) {
            wconv<<<dim3(K2 / 32, 64, 2), dim3(256), 0, stream>>>(Wg_fw, Wc_fw, WgT_fw, WcT_fw, K2);
            wconv<<<dim3(K2 / 32, 64, 2), dim3(256), 0, stream>>>(Wg_bw, Wc_bw, WgT_bw, WcT_bw, K2);
            gemm_projT<<<dim3(64, 24), dim3(256), 0, stream>>>(lin, lda, K, WgT_fw, WcT_fw, K2, bg_fw, bc_fw, projfw);
            gemm_projT<<<dim3(64, 24), dim3(256), 0, stream>>>(lin, lda, K, WgT_bw, WcT_bw, K2, bg_bw, bc_bw, projbw);
        } else {
            gemm_proj<<<dim3(64, 24), dim3(256), 0, stream>>>(lin, lda, K, Wg_fw, Wc_fw, bg_fw, bc_fw, projfw);
            gemm_proj<<<dim3(64, 24), dim3(256), 0, stream>>>(lin, lda, K, Wg_bw, Wc_bw, bg_bw, bc_bw, projbw);
        }

        const float* Wgh_fw = Wg_fw + (size_t)din * 2048;
        const float* Wgh_bw = Wg_bw + (size_t)din * 2048;
        const float* Wch_fw = Wc_fw + (size_t)din * 1024;
        const float* Wch_bw = Wc_bw + (size_t)din * 1024;
        f16* yout = ybufs[l & 1];
        float* stfw = out + 1048576 + l * 32768;
        float* stbw = out + 1048576 + 98304 + l * 32768;
        unsigned* cnt = ctrl + l * 512;

        gru_layer<<<dim3(128), dim3(256), 99072, stream>>>(
            projfw, projbw, Wgh_fw, Wgh_bw, Wch_fw, Wch_bw, h0_fw, h0_bw,
            h16, rh16, u32, yout, stfw, stbw, cnt);
        lin = yout; lda = 2048; K = 2048;
    }

    gemm_fc<<<dim3(64), dim3(256), 0, stream>>>(ybufs[0], fcW, fcb, out);
}

// Round 8
// 6636.612 us; speedup vs baseline: 5.2644x; 1.2230x over previous
//
#include <hip/hip_runtime.h>

typedef _Float16 f16;
typedef _Float16 f16x4 __attribute__((ext_vector_type(4)));
typedef _Float16 f16x8 __attribute__((ext_vector_type(8)));
typedef float f32x4 __attribute__((ext_vector_type(4)));

#define NB 32
#define NT 256
#define NE 256
#define NU 1024
#define NV 128

#define MEMF() asm volatile("" ::: "memory")

// ---------- agent-coherent (cross-XCD, L3-level) load/store helpers ----------
__device__ __forceinline__ unsigned long long cload64(const f16* p) {
    return __hip_atomic_load((const unsigned long long*)p, __ATOMIC_RELAXED,
                             __HIP_MEMORY_SCOPE_AGENT);
}
__device__ __forceinline__ float cloadf(const float* p) {
    return __hip_atomic_load(p, __ATOMIC_RELAXED, __HIP_MEMORY_SCOPE_AGENT);
}
__device__ __forceinline__ void cstoref(float* p, float v) {
    __hip_atomic_store(p, v, __ATOMIC_RELAXED, __HIP_MEMORY_SCOPE_AGENT);
}
__device__ __forceinline__ void cstore16(f16* p, f16 v) {
    __hip_atomic_store((unsigned short*)p, __builtin_bit_cast(unsigned short, v),
                       __ATOMIC_RELAXED, __HIP_MEMORY_SCOPE_AGENT);
}

__device__ __forceinline__ void barsync() {
    MEMF();
    __builtin_amdgcn_s_barrier();
    MEMF();
}

// wave-0 vector poll: lane l watches block l's flag (64B stride). All 64 flags
// in one vector-load round trip per iteration. No atomic RMW anywhere.
__device__ __forceinline__ void gwait(const unsigned* flagd, unsigned target) {
    if (threadIdx.x < 64) {
        int it = 0;
        for (;;) {
            unsigned v = __hip_atomic_load(&flagd[threadIdx.x * 16],
                                           __ATOMIC_RELAXED, __HIP_MEMORY_SCOPE_AGENT);
            if (__all(v >= target)) break;
            __builtin_amdgcn_s_sleep(1);
            if (++it > (1 << 14)) break;  // failsafe: fail visibly, don't hang
        }
    }
}

// full barrier: drain stores -> block sync -> per-block flag store -> poll -> sync
__device__ __forceinline__ void gbar(unsigned* flagd, int lb, unsigned target) {
    asm volatile("s_waitcnt vmcnt(0)" ::: "memory");
    barsync();
    if (threadIdx.x == 0)
        __hip_atomic_store(&flagd[lb * 16], target, __ATOMIC_RELAXED,
                           __HIP_MEMORY_SCOPE_AGENT);
    gwait(flagd, target);
    barsync();
}

// stage 32 rows x 1024 f16 from agent-coherent global into LDS (pitch 1032).
// All 32 loads issued before any LDS write -> one L3 round trip.
__device__ __forceinline__ void stage32(const f16* __restrict__ src,
                                        f16* __restrict__ stg, int tid) {
    unsigned long long a[16], b[16];
    #pragma unroll
    for (int i = 0; i < 16; ++i)
        a[i] = cload64(src + i * NU + tid * 4);
    MEMF();
    #pragma unroll
    for (int i = 0; i < 16; ++i)
        b[i] = cload64(src + (16 + i) * NU + tid * 4);
    MEMF();
    #pragma unroll
    for (int i = 0; i < 16; ++i)
        *(f16x4*)(&stg[i * 1032 + tid * 4]) = __builtin_bit_cast(f16x4, a[i]);
    #pragma unroll
    for (int i = 0; i < 16; ++i)
        *(f16x4*)(&stg[(16 + i) * 1032 + tid * 4]) = __builtin_bit_cast(f16x4, b[i]);
}

// ---------------- embedding ----------------
__global__ void embed_kernel(const int* __restrict__ x, const float* __restrict__ emb,
                             f16* __restrict__ seq0) {
    int row = blockIdx.x;           // t*NB + b
    int t = row >> 5, b = row & 31;
    int e = threadIdx.x;
    int idx = x[b * NT + t];
    seq0[row * NE + e] = (f16)emb[idx * NE + e];
}

// ---------------- weight transpose+convert: WT[n][k] (f16) = W[k][n] (f32) ----------------
__global__ void wconv(const float* __restrict__ Wg, const float* __restrict__ Wc,
                      f16* __restrict__ WgT, f16* __restrict__ WcT, int K2) {
    __shared__ float tile[32][33];
    int mat = blockIdx.z & 1;
    const float* in = mat ? Wc : Wg;
    f16* outp = mat ? WcT : WgT;
    int N = mat ? 1024 : 2048;
    int by = blockIdx.y;
    if (by * 32 >= N) return;
    int k0 = blockIdx.x * 32, n0 = by * 32;
    int tx = threadIdx.x & 31, ty = threadIdx.x >> 5;  // 32 x 8
    #pragma unroll
    for (int i = 0; i < 4; ++i) {
        int r = ty * 4 + i;
        tile[r][tx] = in[(size_t)(k0 + r) * N + n0 + tx];
    }
    __syncthreads();
    #pragma unroll
    for (int i = 0; i < 4; ++i) {
        int rn = ty * 4 + i;
        outp[(size_t)(n0 + rn) * K2 + k0 + tx] = (f16)tile[tx][rn];
    }
}

// ---------------- input-projection GEMM, f16 transposed-weight edition ----------------
__launch_bounds__(256)
__global__ void gemm_projT(const f16* __restrict__ A, int lda, int K,
                           const f16* __restrict__ WgT, const f16* __restrict__ WcT, int K2,
                           const float* __restrict__ bg, const float* __restrict__ bc,
                           f16* __restrict__ proj) {
    __shared__ f16 As[128][40];
    __shared__ f16 Bs[128][40];
    int cb = blockIdx.y;
    const f16* Bsrc; int outcol; const float* bias;
    if (cb < 16) { Bsrc = WgT + (size_t)cb * 128 * K2; outcol = cb * 128; bias = bg + cb * 128; }
    else { Bsrc = WcT + (size_t)(cb - 16) * 128 * K2; outcol = 2048 + (cb - 16) * 128; bias = bc + (cb - 16) * 128; }
    int m0 = blockIdx.x * 128;
    int tid = threadIdx.x;
    int w = tid >> 6, l = tid & 63;
    int wm = w & 1, wn = w >> 1;
    f32x4 acc[4][4] = {};
    for (int k0 = 0; k0 < K; k0 += 32) {
        __syncthreads();
        #pragma unroll
        for (int p = 0; p < 2; ++p) {
            int e = (p * 256 + tid) * 8;
            int r = e >> 5, kq = e & 31;
            f16x8 v = *(const f16x8*)(A + (size_t)(m0 + r) * lda + k0 + kq);
            *(f16x8*)(&As[r][kq]) = v;
        }
        #pragma unroll
        for (int p = 0; p < 2; ++p) {
            int e = (p * 256 + tid) * 8;
            int r = e >> 5, kq = e & 31;
            f16x8 v = *(const f16x8*)(Bsrc + (size_t)r * K2 + k0 + kq);
            *(f16x8*)(&Bs[r][kq]) = v;
        }
        __syncthreads();
        int kq = (l >> 4) * 8;
        f16x8 a[4], b[4];
        #pragma unroll
        for (int i = 0; i < 4; ++i) a[i] = *(const f16x8*)(&As[wm * 64 + i * 16 + (l & 15)][kq]);
        #pragma unroll
        for (int j = 0; j < 4; ++j) b[j] = *(const f16x8*)(&Bs[wn * 64 + j * 16 + (l & 15)][kq]);
        #pragma unroll
        for (int i = 0; i < 4; ++i)
            #pragma unroll
            for (int j = 0; j < 4; ++j)
                acc[i][j] = __builtin_amdgcn_mfma_f32_16x16x32_f16(a[i], b[j], acc[i][j], 0, 0, 0);
    }
    int lr = (l >> 4) * 4, lc = l & 15;
    #pragma unroll
    for (int i = 0; i < 4; ++i) {
        #pragma unroll
        for (int j = 0; j < 4; ++j) {
            int gcol = wn * 64 + j * 16 + lc;
            float bia = bias[gcol];
            #pragma unroll
            for (int q = 0; q < 4; ++q) {
                int grow = m0 + wm * 64 + i * 16 + lr + q;
                proj[(size_t)grow * 3072 + outcol + gcol] = (f16)(acc[i][j][q] + bia);
            }
        }
    }
}

// ---------------- input-projection GEMM (fallback, f32 weights) ----------------
__launch_bounds__(256)
__global__ void gemm_proj(const f16* __restrict__ A, int lda, int K,
                          const float* __restrict__ Wg, const float* __restrict__ Wc,
                          const float* __restrict__ bg, const float* __restrict__ bc,
                          f16* __restrict__ proj) {
    __shared__ f16 As[128][40];
    __shared__ f16 Bs[128][40];
    int cb = blockIdx.y;
    const float* Bsrc; int ldb, outcol; const float* bias;
    if (cb < 16) { Bsrc = Wg + cb * 128; ldb = 2 * NU; outcol = cb * 128; bias = bg + cb * 128; }
    else { Bsrc = Wc + (cb - 16) * 128; ldb = NU; outcol = 2 * NU + (cb - 16) * 128; bias = bc + (cb - 16) * 128; }
    int m0 = blockIdx.x * 128;
    int tid = threadIdx.x;
    int w = tid >> 6, l = tid & 63;
    int wm = w & 1, wn = w >> 1;
    f32x4 acc[4][4] = {};
    for (int k0 = 0; k0 < K; k0 += 32) {
        __syncthreads();
        #pragma unroll
        for (int p = 0; p < 2; ++p) {
            int e = (p * 256 + tid) * 8;
            int r = e >> 5, kq = e & 31;
            f16x8 v = *(const f16x8*)(A + (size_t)(m0 + r) * lda + k0 + kq);
            *(f16x8*)(&As[r][kq]) = v;
        }
        #pragma unroll
        for (int p = 0; p < 4; ++p) {
            int k = p * 8 + (tid >> 5);
            int n = (tid & 31) * 4;
            float4 v = *(const float4*)(Bsrc + (size_t)(k0 + k) * ldb + n);
            Bs[n + 0][k] = (f16)v.x; Bs[n + 1][k] = (f16)v.y;
            Bs[n + 2][k] = (f16)v.z; Bs[n + 3][k] = (f16)v.w;
        }
        __syncthreads();
        int kq = (l >> 4) * 8;
        f16x8 a[4], b[4];
        #pragma unroll
        for (int i = 0; i < 4; ++i) a[i] = *(const f16x8*)(&As[wm * 64 + i * 16 + (l & 15)][kq]);
        #pragma unroll
        for (int j = 0; j < 4; ++j) b[j] = *(const f16x8*)(&Bs[wn * 64 + j * 16 + (l & 15)][kq]);
        #pragma unroll
        for (int i = 0; i < 4; ++i)
            #pragma unroll
            for (int j = 0; j < 4; ++j)
                acc[i][j] = __builtin_amdgcn_mfma_f32_16x16x32_f16(a[i], b[j], acc[i][j], 0, 0, 0);
    }
    int lr = (l >> 4) * 4, lc = l & 15;
    #pragma unroll
    for (int i = 0; i < 4; ++i) {
        #pragma unroll
        for (int j = 0; j < 4; ++j) {
            int gcol = wn * 64 + j * 16 + lc;
            float bia = bias[gcol];
            #pragma unroll
            for (int q = 0; q < 4; ++q) {
                int grow = m0 + wm * 64 + i * 16 + lr + q;
                proj[(size_t)grow * 3072 + outcol + gcol] = (f16)(acc[i][j][q] + bia);
            }
        }
    }
}

// ---------------- final FC ----------------
__launch_bounds__(256)
__global__ void gemm_fc(const f16* __restrict__ y, const float* __restrict__ W,
                        const float* __restrict__ bias, float* __restrict__ out) {
    __shared__ f16 As[128][40];
    __shared__ f16 Bs[128][40];
    int m0 = blockIdx.x * 128;
    int tid = threadIdx.x;
    int w = tid >> 6, l = tid & 63;
    int wm = w & 1, wn = w >> 1;
    f32x4 acc[4][4] = {};
    for (int k0 = 0; k0 < 2048; k0 += 32) {
        __syncthreads();
        #pragma unroll
        for (int p = 0; p < 2; ++p) {
            int e = (p * 256 + tid) * 8;
            int r = e >> 5, kq = e & 31;
            int grow = m0 + r;                 // row = b*256 + t
            int b = grow >> 8, t = grow & 255;
            f16x8 v = *(const f16x8*)(y + (size_t)(t * 32 + b) * 2048 + k0 + kq);
            *(f16x8*)(&As[r][kq]) = v;
        }
        #pragma unroll
        for (int p = 0; p < 4; ++p) {
            int k = p * 8 + (tid >> 5);
            int n = (tid & 31) * 4;
            float4 v = *(const float4*)(W + (size_t)(k0 + k) * 128 + n);
            Bs[n + 0][k] = (f16)v.x; Bs[n + 1][k] = (f16)v.y;
            Bs[n + 2][k] = (f16)v.z; Bs[n + 3][k] = (f16)v.w;
        }
        __syncthreads();
        int kq = (l >> 4) * 8;
        f16x8 a[4], b[4];
        #pragma unroll
        for (int i = 0; i < 4; ++i) a[i] = *(const f16x8*)(&As[wm * 64 + i * 16 + (l & 15)][kq]);
        #pragma unroll
        for (int j = 0; j < 4; ++j) b[j] = *(const f16x8*)(&Bs[wn * 64 + j * 16 + (l & 15)][kq]);
        #pragma unroll
        for (int i = 0; i < 4; ++i)
            #pragma unroll
            for (int j = 0; j < 4; ++j)
                acc[i][j] = __builtin_amdgcn_mfma_f32_16x16x32_f16(a[i], b[j], acc[i][j], 0, 0, 0);
    }
    int lr = (l >> 4) * 4, lc = l & 15;
    #pragma unroll
    for (int i = 0; i < 4; ++i) {
        #pragma unroll
        for (int j = 0; j < 4; ++j) {
            int gcol = wn * 64 + j * 16 + lc;
            float bia = bias[gcol];
            #pragma unroll
            for (int q = 0; q < 4; ++q) {
                int grow = m0 + wm * 64 + i * 16 + lr + q;
                out[(size_t)grow * 128 + gcol] = acc[i][j][q] + bia;
            }
        }
    }
}

// ---------------- recurrent bidirectional GRU layer (r7 skeleton, flag barrier) ----------
__launch_bounds__(256)
__global__ void gru_layer(
    const f16* __restrict__ proj_fw, const f16* __restrict__ proj_bw,
    const float* __restrict__ Wgh_fw, const float* __restrict__ Wgh_bw,
    const float* __restrict__ Wch_fw, const float* __restrict__ Wch_bw,
    const float* __restrict__ h0_fw, const float* __restrict__ h0_bw,
    f16* __restrict__ h16, f16* __restrict__ rh16, float* __restrict__ u32,
    f16* __restrict__ y, float* __restrict__ st_fw, float* __restrict__ st_bw,
    unsigned* __restrict__ cnt)
{
    extern __shared__ f16 smem[];
    f16* stg    = smem;             // [32][1032]
    f16* Wc_lds = smem + 32 * 1032; // [16][1032]

    int bid = blockIdx.x, tid = threadIdx.x;
    int dir = bid >> 6, lb = bid & 63;
    int gcb = lb * 32;   // gate col base (0..2047)
    int ccb = lb * 16;   // cand col base (0..1023)

    const f16*  proj = dir ? proj_bw : proj_fw;
    const float* Wgh = dir ? Wgh_bw : Wgh_fw;
    const float* Wch = dir ? Wch_bw : Wch_fw;
    const float* h0  = dir ? h0_bw  : h0_fw;
    f16*   h16d  = h16  + dir * (NB * NU);
    f16*   rh16d = rh16 + dir * (NB * NU);
    float* u32d  = u32  + dir * (NB * NU);
    unsigned* flagd = cnt + dir * 1024;   // 64 flags x 16 u32 stride (64B)

    int w = tid >> 6, l = tid & 63;
    int lc = l & 15, lr = (l >> 4) * 4, kq = (l >> 4) * 8;
    int wm = w & 1, wn = w >> 1, wb = w & 1;

    // ---- Wc slice into LDS (proven) ----
    {
        int j2 = tid & 15;
        for (int k = tid >> 4; k < NU; k += 16)
            Wc_lds[j2 * 1032 + k] = (f16)Wch[(size_t)k * 1024 + ccb + j2];
    }

    // ---- Wg fragments -> registers (proven) ----
    f16x8 wgf[32];
    {
        int col = gcb + wn * 16 + lc;
        #pragma unroll
        for (int kt = 0; kt < 32; ++kt) {
            f16x8 t;
            #pragma unroll
            for (int e = 0; e < 8; ++e)
                t[e] = (f16)Wgh[(size_t)(kt * 32 + kq + e) * 2048 + col];
            wgf[kt] = t;
        }
    }

    // ---- init h: publish h16 (disjoint slices); cand h in regs ----
    {
        int base = lb * 512;
        for (int i = tid; i < 512; i += 256)
            cstore16(h16d + base + i, (f16)h0[base + i]);
    }
    f32x4 hreg = {};
    if (w < 2) {
        #pragma unroll
        for (int q = 0; q < 4; ++q)
            hreg[q] = h0[(size_t)(wb * 16 + lr + q) * NU + ccb + lc];
    }

    unsigned bc = 1;
    gbar(flagd, lb, bc);

    int cc = ccb + lc;
    for (int tl = 0; tl < NT; ++tl) {
        int td = dir ? (NT - 1 - tl) : tl;
        const f16* projrow = proj + (size_t)td * NB * 3072;

        // ---- prefetch this step's proj operands ----
        f16 pg[4], pc[4];
        {
            int gc = gcb + wn * 16 + lc;
            int cc2 = 2048 + ccb + lc;
            #pragma unroll
            for (int q = 0; q < 4; ++q) {
                pg[q] = projrow[(size_t)(wm * 16 + lr + q) * 3072 + gc];
                pc[q] = projrow[(size_t)(wb * 16 + lr + q) * 3072 + cc2];
            }
        }

        // ---- stage h16 -> LDS ----
        stage32(h16d, stg, tid);
        asm volatile("s_waitcnt lgkmcnt(0)" ::: "memory");
        __builtin_amdgcn_sched_barrier(0);
        barsync();

        // ---- phase A: ru = sigmoid(proj_g + h @ Wg_h) ----
        {
            const f16* ap = &stg[(wm * 16 + lc) * 1032 + kq];
            f32x4 acc0 = {}, acc1 = {};
            #pragma unroll
            for (int kt = 0; kt < 32; kt += 2) {
                f16x8 a0 = *(const f16x8*)(ap + kt * 32);
                f16x8 a1 = *(const f16x8*)(ap + (kt + 1) * 32);
                acc0 = __builtin_amdgcn_mfma_f32_16x16x32_f16(a0, wgf[kt], acc0, 0, 0, 0);
                acc1 = __builtin_amdgcn_mfma_f32_16x16x32_f16(a1, wgf[kt + 1], acc1, 0, 0, 0);
            }
            f32x4 acc = acc0 + acc1;
            int gc = gcb + wn * 16 + lc;
            #pragma unroll
            for (int q = 0; q < 4; ++q) {
                int br = wm * 16 + lr + q;
                float pre = acc[q] + (float)pg[q];
                float sg = 1.f / (1.f + __expf(-pre));
                if (gc < NU) {   // r-block (block-uniform): rh from staged h16
                    float hv = (float)stg[br * 1032 + gc];
                    cstore16(rh16d + br * NU + gc, (f16)(sg * hv));
                } else {         // u-block
                    cstoref(u32d + br * NU + gc - NU, sg);
                }
            }
        }
        ++bc;
        gbar(flagd, lb, bc);   // barrier #1: rh/u published

        // ---- early u loads (published at barrier #1; overlap with rh stage) ----
        float uu[4];
        if (w < 2) {
            #pragma unroll
            for (int q = 0; q < 4; ++q)
                uu[q] = cloadf(u32d + (wb * 16 + lr + q) * NU + cc);
        }

        // ---- stage rh16 -> LDS ----
        stage32(rh16d, stg, tid);
        asm volatile("s_waitcnt lgkmcnt(0)" ::: "memory");
        __builtin_amdgcn_sched_barrier(0);
        barsync();

        // ---- phase B: c = tanh(proj_c + (r*h) @ Wc_h); h = u*h + (1-u)*c ----
        if (w < 2) {
            const f16* ap = &stg[(wb * 16 + lc) * 1032 + kq];
            const f16* bptr = Wc_lds + lc * 1032 + kq;
            f32x4 acc0 = {}, acc1 = {};
            #pragma unroll
            for (int kt = 0; kt < 32; kt += 2) {
                f16x8 a0 = *(const f16x8*)(ap + kt * 32);
                f16x8 a1 = *(const f16x8*)(ap + (kt + 1) * 32);
                f16x8 b0 = *(const f16x8*)(bptr + kt * 32);
                f16x8 b1 = *(const f16x8*)(bptr + kt * 32 + 32);
                acc0 = __builtin_amdgcn_mfma_f32_16x16x32_f16(a0, b0, acc0, 0, 0, 0);
                acc1 = __builtin_amdgcn_mfma_f32_16x16x32_f16(a1, b1, acc1, 0, 0, 0);
            }
            f32x4 acc = acc0 + acc1;
            #pragma unroll
            for (int q = 0; q < 4; ++q) {
                int br = wb * 16 + lr + q;
                float pre = acc[q] + (float)pc[q];
                float e2 = __expf(2.f * pre);
                float c = 1.f - 2.f / (e2 + 1.f);   // tanh(pre)
                float hn = uu[q] * hreg[q] + (1.f - uu[q]) * c;
                hreg[q] = hn;
                cstore16(h16d + br * NU + cc, (f16)hn);
            }
        }
        ++bc;
        // barrier #2 inline: drain h16, arrive, THEN y/state stores, then wait
        asm volatile("s_waitcnt vmcnt(0)" ::: "memory");
        barsync();
        if (tid == 0)
            __hip_atomic_store(&flagd[lb * 16], bc, __ATOMIC_RELAXED,
                               __HIP_MEMORY_SCOPE_AGENT);
        if (w < 2) {
            #pragma unroll
            for (int q = 0; q < 4; ++q) {
                int br = wb * 16 + lr + q;
                y[(size_t)(td * NB + br) * 2048 + dir * NU + cc] = (f16)hreg[q];
                if (tl == NT - 1)
                    (dir ? st_bw : st_fw)[br * NU + cc] = hreg[q];
            }
        }
        gwait(flagd, bc);
        barsync();
    }
}

// ---------------- host launch ----------------
extern "C" void kernel_launch(void* const* d_in, const int* in_sizes, int n_in,
                              void* d_out, int out_size, void* d_ws, size_t ws_size,
                              hipStream_t stream) {
    const int*   x   = (const int*)  d_in[0];
    const float* emb = (const float*)d_in[1];
    const float* fcW = (const float*)d_in[2];
    const float* fcb = (const float*)d_in[3];
    float* out = (float*)d_out;

    char* ws = (char*)d_ws;
    size_t off = 0;
    f16* seq0   = (f16*)(ws + off); off += (size_t)8192 * 256 * 2;
    f16* ybuf0  = (f16*)(ws + off); off += (size_t)8192 * 2048 * 2;
    f16* ybuf1  = (f16*)(ws + off); off += (size_t)8192 * 2048 * 2;
    f16* projfw = (f16*)(ws + off); off += (size_t)8192 * 3072 * 2;
    f16* projbw = (f16*)(ws + off); off += (size_t)8192 * 3072 * 2;
    f16*   h16  = (f16*)(ws + off);   off += 2 * 32 * 1024 * 2;
    f16*   rh16 = (f16*)(ws + off);   off += 2 * 32 * 1024 * 2;
    float* u32  = (float*)(ws + off); off += 2 * 32 * 1024 * 4;
    unsigned* ctrl = (unsigned*)(ws + off); off += 3 * 8192;   // 3 layers x 2048 u32
    // per-layer-reused f16 transposed-weight slot (max-layer sizes, K2=3072)
    f16* WgT_fw = (f16*)(ws + off); off += (size_t)2048 * 3072 * 2;
    f16* WgT_bw = (f16*)(ws + off); off += (size_t)2048 * 3072 * 2;
    f16* WcT_fw = (f16*)(ws + off); off += (size_t)1024 * 3072 * 2;
    f16* WcT_bw = (f16*)(ws + off); off += (size_t)1024 * 3072 * 2;
    bool cvt = (ws_size >= off);   // fall back to f32 gemm if slot doesn't fit

    hipFuncSetAttribute((const void*)gru_layer,
                        hipFuncAttributeMaxDynamicSharedMemorySize, 99072);

    hipMemsetAsync(ctrl, 0, 3 * 8192, stream);
    embed_kernel<<<dim3(8192), dim3(256), 0, stream>>>(x, emb, seq0);

    const f16* lin = seq0; int lda = 256, K = 256;
    f16* ybufs[2] = {ybuf0, ybuf1};
    for (int l = 0; l < 3; ++l) {
        const float* Wg_fw = (const float*)d_in[4 + l * 10 + 0];
        const float* bg_fw = (const float*)d_in[4 + l * 10 + 1];
        const float* Wc_fw = (const float*)d_in[4 + l * 10 + 2];
        const float* bc_fw = (const float*)d_in[4 + l * 10 + 3];
        const float* h0_fw = (const float*)d_in[4 + l * 10 + 4];
        const float* Wg_bw = (const float*)d_in[4 + l * 10 + 5];
        const float* bg_bw = (const float*)d_in[4 + l * 10 + 6];
        const float* Wc_bw = (const float*)d_in[4 + l * 10 + 7];
        const float* bc_bw = (const float*)d_in[4 + l * 10 + 8];
        const float* h0_bw = (const float*)d_in[4 + l * 10 + 9];
        int din = (l == 0) ? 256 : 2048;
        int K2 = din + 1024;

        if (cvt) {
            wconv<<<dim3(K2 / 32, 64, 2), dim3(256), 0, stream>>>(Wg_fw, Wc_fw, WgT_fw, WcT_fw, K2);
            wconv<<<dim3(K2 / 32, 64, 2), dim3(256), 0, stream>>>(Wg_bw, Wc_bw, WgT_bw, WcT_bw, K2);
            gemm_projT<<<dim3(64, 24), dim3(256), 0, stream>>>(lin, lda, K, WgT_fw, WcT_fw, K2, bg_fw, bc_fw, projfw);
            gemm_projT<<<dim3(64, 24), dim3(256), 0, stream>>>(lin, lda, K, WgT_bw, WcT_bw, K2, bg_bw, bc_bw, projbw);
        } else {
            gemm_proj<<<dim3(64, 24), dim3(256), 0, stream>>>(lin, lda, K, Wg_fw, Wc_fw, bg_fw, bc_fw, projfw);
            gemm_proj<<<dim3(64, 24), dim3(256), 0, stream>>>(lin, lda, K, Wg_bw, Wc_bw, bg_bw, bc_bw, projbw);
        }

        const float* Wgh_fw = Wg_fw + (size_t)din * 2048;
        const float* Wgh_bw = Wg_bw + (size_t)din * 2048;
        const float* Wch_fw = Wc_fw + (size_t)din * 1024;
        const float* Wch_bw = Wc_bw + (size_t)din * 1024;
        f16* yout = ybufs[l & 1];
        float* stfw = out + 1048576 + l * 32768;
        float* stbw = out + 1048576 + 98304 + l * 32768;
        unsigned* cnt = ctrl + l * 2048;

        gru_layer<<<dim3(128), dim3(256), 99072, stream>>>(
            projfw, projbw, Wgh_fw, Wgh_bw, Wch_fw, Wch_bw, h0_fw, h0_bw,
            h16, rh16, u32, yout, stfw, stbw, cnt);
        lin = yout; lda = 2048; K = 2048;
    }

    gemm_fc<<<dim3(64), dim3(256), 0, stream>>>(ybufs[0], fcW, fcb, out);
}

// Round 9
// 6462.744 us; speedup vs baseline: 5.4061x; 1.0269x over previous
//
#include <hip/hip_runtime.h>

typedef _Float16 f16;
typedef _Float16 f16x4 __attribute__((ext_vector_type(4)));
typedef _Float16 f16x8 __attribute__((ext_vector_type(8)));
typedef float f32x4 __attribute__((ext_vector_type(4)));

#define NB 32
#define NT 256
#define NE 256
#define NU 1024
#define NV 128

#define MEMF() asm volatile("" ::: "memory")

// ---------- agent-coherent (cross-XCD, L3-level) load/store helpers ----------
__device__ __forceinline__ unsigned long long cload64(const f16* p) {
    return __hip_atomic_load((const unsigned long long*)p, __ATOMIC_RELAXED,
                             __HIP_MEMORY_SCOPE_AGENT);
}
__device__ __forceinline__ float cloadf(const float* p) {
    return __hip_atomic_load(p, __ATOMIC_RELAXED, __HIP_MEMORY_SCOPE_AGENT);
}
__device__ __forceinline__ void cstoref(float* p, float v) {
    __hip_atomic_store(p, v, __ATOMIC_RELAXED, __HIP_MEMORY_SCOPE_AGENT);
}
__device__ __forceinline__ void cstore16(f16* p, f16 v) {
    __hip_atomic_store((unsigned short*)p, __builtin_bit_cast(unsigned short, v),
                       __ATOMIC_RELAXED, __HIP_MEMORY_SCOPE_AGENT);
}

__device__ __forceinline__ void barsync() {
    MEMF();
    __builtin_amdgcn_s_barrier();
    MEMF();
}

// wave-0 vector poll: lane l watches block l's flag (64B stride). All 64 flags
// in one vector-load round trip per iteration; no sleep (load self-throttles).
__device__ __forceinline__ void gwait(const unsigned* flagd, unsigned target) {
    if (threadIdx.x < 64) {
        int it = 0;
        for (;;) {
            unsigned v = __hip_atomic_load(&flagd[threadIdx.x * 16],
                                           __ATOMIC_RELAXED, __HIP_MEMORY_SCOPE_AGENT);
            if (__all(v >= target)) break;
            if (++it > (1 << 16)) break;  // failsafe: fail visibly, don't hang
        }
    }
}

// full barrier: drain stores -> block sync -> per-block flag store -> poll -> sync
__device__ __forceinline__ void gbar(unsigned* flagd, int lb, unsigned target) {
    asm volatile("s_waitcnt vmcnt(0)" ::: "memory");
    barsync();
    if (threadIdx.x == 0)
        __hip_atomic_store(&flagd[lb * 16], target, __ATOMIC_RELAXED,
                           __HIP_MEMORY_SCOPE_AGENT);
    gwait(flagd, target);
    barsync();
}

// stage 32 rows x 1024 f16 from agent-coherent global into LDS (pitch 1032).
// All 32 loads issued before any LDS write -> one L3 round trip.
__device__ __forceinline__ void stage32(const f16* __restrict__ src,
                                        f16* __restrict__ stg, int tid) {
    unsigned long long a[16], b[16];
    #pragma unroll
    for (int i = 0; i < 16; ++i)
        a[i] = cload64(src + i * NU + tid * 4);
    MEMF();
    #pragma unroll
    for (int i = 0; i < 16; ++i)
        b[i] = cload64(src + (16 + i) * NU + tid * 4);
    MEMF();
    #pragma unroll
    for (int i = 0; i < 16; ++i)
        *(f16x4*)(&stg[i * 1032 + tid * 4]) = __builtin_bit_cast(f16x4, a[i]);
    #pragma unroll
    for (int i = 0; i < 16; ++i)
        *(f16x4*)(&stg[(16 + i) * 1032 + tid * 4]) = __builtin_bit_cast(f16x4, b[i]);
}

// ---------------- embedding ----------------
__global__ void embed_kernel(const int* __restrict__ x, const float* __restrict__ emb,
                             f16* __restrict__ seq0) {
    int row = blockIdx.x;           // t*NB + b
    int t = row >> 5, b = row & 31;
    int e = threadIdx.x;
    int idx = x[b * NT + t];
    seq0[row * NE + e] = (f16)emb[idx * NE + e];
}

// ---------------- weight transpose+convert: WT[n][k] (f16) = W[k][n] (f32) ----------------
__global__ void wconv(const float* __restrict__ Wg, const float* __restrict__ Wc,
                      f16* __restrict__ WgT, f16* __restrict__ WcT, int K2) {
    __shared__ float tile[32][33];
    int mat = blockIdx.z & 1;
    const float* in = mat ? Wc : Wg;
    f16* outp = mat ? WcT : WgT;
    int N = mat ? 1024 : 2048;
    int by = blockIdx.y;
    if (by * 32 >= N) return;
    int k0 = blockIdx.x * 32, n0 = by * 32;
    int tx = threadIdx.x & 31, ty = threadIdx.x >> 5;  // 32 x 8
    #pragma unroll
    for (int i = 0; i < 4; ++i) {
        int r = ty * 4 + i;
        tile[r][tx] = in[(size_t)(k0 + r) * N + n0 + tx];
    }
    __syncthreads();
    #pragma unroll
    for (int i = 0; i < 4; ++i) {
        int rn = ty * 4 + i;
        outp[(size_t)(n0 + rn) * K2 + k0 + tx] = (f16)tile[tx][rn];
    }
}

// ---------------- input-projection GEMM, f16 transposed-weight edition ----------------
__launch_bounds__(256)
__global__ void gemm_projT(const f16* __restrict__ A, int lda, int K,
                           const f16* __restrict__ WgT, const f16* __restrict__ WcT, int K2,
                           const float* __restrict__ bg, const float* __restrict__ bc,
                           f16* __restrict__ proj) {
    __shared__ f16 As[128][40];
    __shared__ f16 Bs[128][40];
    int cb = blockIdx.y;
    const f16* Bsrc; int outcol; const float* bias;
    if (cb < 16) { Bsrc = WgT + (size_t)cb * 128 * K2; outcol = cb * 128; bias = bg + cb * 128; }
    else { Bsrc = WcT + (size_t)(cb - 16) * 128 * K2; outcol = 2048 + (cb - 16) * 128; bias = bc + (cb - 16) * 128; }
    int m0 = blockIdx.x * 128;
    int tid = threadIdx.x;
    int w = tid >> 6, l = tid & 63;
    int wm = w & 1, wn = w >> 1;
    f32x4 acc[4][4] = {};
    for (int k0 = 0; k0 < K; k0 += 32) {
        __syncthreads();
        #pragma unroll
        for (int p = 0; p < 2; ++p) {
            int e = (p * 256 + tid) * 8;
            int r = e >> 5, kq = e & 31;
            f16x8 v = *(const f16x8*)(A + (size_t)(m0 + r) * lda + k0 + kq);
            *(f16x8*)(&As[r][kq]) = v;
        }
        #pragma unroll
        for (int p = 0; p < 2; ++p) {
            int e = (p * 256 + tid) * 8;
            int r = e >> 5, kq = e & 31;
            f16x8 v = *(const f16x8*)(Bsrc + (size_t)r * K2 + k0 + kq);
            *(f16x8*)(&Bs[r][kq]) = v;
        }
        __syncthreads();
        int kq = (l >> 4) * 8;
        f16x8 a[4], b[4];
        #pragma unroll
        for (int i = 0; i < 4; ++i) a[i] = *(const f16x8*)(&As[wm * 64 + i * 16 + (l & 15)][kq]);
        #pragma unroll
        for (int j = 0; j < 4; ++j) b[j] = *(const f16x8*)(&Bs[wn * 64 + j * 16 + (l & 15)][kq]);
        #pragma unroll
        for (int i = 0; i < 4; ++i)
            #pragma unroll
            for (int j = 0; j < 4; ++j)
                acc[i][j] = __builtin_amdgcn_mfma_f32_16x16x32_f16(a[i], b[j], acc[i][j], 0, 0, 0);
    }
    int lr = (l >> 4) * 4, lc = l & 15;
    #pragma unroll
    for (int i = 0; i < 4; ++i) {
        #pragma unroll
        for (int j = 0; j < 4; ++j) {
            int gcol = wn * 64 + j * 16 + lc;
            float bia = bias[gcol];
            #pragma unroll
            for (int q = 0; q < 4; ++q) {
                int grow = m0 + wm * 64 + i * 16 + lr + q;
                proj[(size_t)grow * 3072 + outcol + gcol] = (f16)(acc[i][j][q] + bia);
            }
        }
    }
}

// ---------------- input-projection GEMM (fallback, f32 weights) ----------------
__launch_bounds__(256)
__global__ void gemm_proj(const f16* __restrict__ A, int lda, int K,
                          const float* __restrict__ Wg, const float* __restrict__ Wc,
                          const float* __restrict__ bg, const float* __restrict__ bc,
                          f16* __restrict__ proj) {
    __shared__ f16 As[128][40];
    __shared__ f16 Bs[128][40];
    int cb = blockIdx.y;
    const float* Bsrc; int ldb, outcol; const float* bias;
    if (cb < 16) { Bsrc = Wg + cb * 128; ldb = 2 * NU; outcol = cb * 128; bias = bg + cb * 128; }
    else { Bsrc = Wc + (cb - 16) * 128; ldb = NU; outcol = 2 * NU + (cb - 16) * 128; bias = bc + (cb - 16) * 128; }
    int m0 = blockIdx.x * 128;
    int tid = threadIdx.x;
    int w = tid >> 6, l = tid & 63;
    int wm = w & 1, wn = w >> 1;
    f32x4 acc[4][4] = {};
    for (int k0 = 0; k0 < K; k0 += 32) {
        __syncthreads();
        #pragma unroll
        for (int p = 0; p < 2; ++p) {
            int e = (p * 256 + tid) * 8;
            int r = e >> 5, kq = e & 31;
            f16x8 v = *(const f16x8*)(A + (size_t)(m0 + r) * lda + k0 + kq);
            *(f16x8*)(&As[r][kq]) = v;
        }
        #pragma unroll
        for (int p = 0; p < 4; ++p) {
            int k = p * 8 + (tid >> 5);
            int n = (tid & 31) * 4;
            float4 v = *(const float4*)(Bsrc + (size_t)(k0 + k) * ldb + n);
            Bs[n + 0][k] = (f16)v.x; Bs[n + 1][k] = (f16)v.y;
            Bs[n + 2][k] = (f16)v.z; Bs[n + 3][k] = (f16)v.w;
        }
        __syncthreads();
        int kq = (l >> 4) * 8;
        f16x8 a[4], b[4];
        #pragma unroll
        for (int i = 0; i < 4; ++i) a[i] = *(const f16x8*)(&As[wm * 64 + i * 16 + (l & 15)][kq]);
        #pragma unroll
        for (int j = 0; j < 4; ++j) b[j] = *(const f16x8*)(&Bs[wn * 64 + j * 16 + (l & 15)][kq]);
        #pragma unroll
        for (int i = 0; i < 4; ++i)
            #pragma unroll
            for (int j = 0; j < 4; ++j)
                acc[i][j] = __builtin_amdgcn_mfma_f32_16x16x32_f16(a[i], b[j], acc[i][j], 0, 0, 0);
    }
    int lr = (l >> 4) * 4, lc = l & 15;
    #pragma unroll
    for (int i = 0; i < 4; ++i) {
        #pragma unroll
        for (int j = 0; j < 4; ++j) {
            int gcol = wn * 64 + j * 16 + lc;
            float bia = bias[gcol];
            #pragma unroll
            for (int q = 0; q < 4; ++q) {
                int grow = m0 + wm * 64 + i * 16 + lr + q;
                proj[(size_t)grow * 3072 + outcol + gcol] = (f16)(acc[i][j][q] + bia);
            }
        }
    }
}

// ---------------- final FC ----------------
__launch_bounds__(256)
__global__ void gemm_fc(const f16* __restrict__ y, const float* __restrict__ W,
                        const float* __restrict__ bias, float* __restrict__ out) {
    __shared__ f16 As[128][40];
    __shared__ f16 Bs[128][40];
    int m0 = blockIdx.x * 128;
    int tid = threadIdx.x;
    int w = tid >> 6, l = tid & 63;
    int wm = w & 1, wn = w >> 1;
    f32x4 acc[4][4] = {};
    for (int k0 = 0; k0 < 2048; k0 += 32) {
        __syncthreads();
        #pragma unroll
        for (int p = 0; p < 2; ++p) {
            int e = (p * 256 + tid) * 8;
            int r = e >> 5, kq = e & 31;
            int grow = m0 + r;                 // row = b*256 + t
            int b = grow >> 8, t = grow & 255;
            f16x8 v = *(const f16x8*)(y + (size_t)(t * 32 + b) * 2048 + k0 + kq);
            *(f16x8*)(&As[r][kq]) = v;
        }
        #pragma unroll
        for (int p = 0; p < 4; ++p) {
            int k = p * 8 + (tid >> 5);
            int n = (tid & 31) * 4;
            float4 v = *(const float4*)(W + (size_t)(k0 + k) * 128 + n);
            Bs[n + 0][k] = (f16)v.x; Bs[n + 1][k] = (f16)v.y;
            Bs[n + 2][k] = (f16)v.z; Bs[n + 3][k] = (f16)v.w;
        }
        __syncthreads();
        int kq = (l >> 4) * 8;
        f16x8 a[4], b[4];
        #pragma unroll
        for (int i = 0; i < 4; ++i) a[i] = *(const f16x8*)(&As[wm * 64 + i * 16 + (l & 15)][kq]);
        #pragma unroll
        for (int j = 0; j < 4; ++j) b[j] = *(const f16x8*)(&Bs[wn * 64 + j * 16 + (l & 15)][kq]);
        #pragma unroll
        for (int i = 0; i < 4; ++i)
            #pragma unroll
            for (int j = 0; j < 4; ++j)
                acc[i][j] = __builtin_amdgcn_mfma_f32_16x16x32_f16(a[i], b[j], acc[i][j], 0, 0, 0);
    }
    int lr = (l >> 4) * 4, lc = l & 15;
    #pragma unroll
    for (int i = 0; i < 4; ++i) {
        #pragma unroll
        for (int j = 0; j < 4; ++j) {
            int gcol = wn * 64 + j * 16 + lc;
            float bia = bias[gcol];
            #pragma unroll
            for (int q = 0; q < 4; ++q) {
                int grow = m0 + wm * 64 + i * 16 + lr + q;
                out[(size_t)grow * 128 + gcol] = acc[i][j][q] + bia;
            }
        }
    }
}

// ---------------- recurrent bidirectional GRU layer (r8 skeleton + proj pipelining) -------
__launch_bounds__(256)
__global__ void gru_layer(
    const f16* __restrict__ proj_fw, const f16* __restrict__ proj_bw,
    const float* __restrict__ Wgh_fw, const float* __restrict__ Wgh_bw,
    const float* __restrict__ Wch_fw, const float* __restrict__ Wch_bw,
    const float* __restrict__ h0_fw, const float* __restrict__ h0_bw,
    f16* __restrict__ h16, f16* __restrict__ rh16, float* __restrict__ u32,
    f16* __restrict__ y, float* __restrict__ st_fw, float* __restrict__ st_bw,
    unsigned* __restrict__ cnt)
{
    extern __shared__ f16 smem[];
    f16* stg    = smem;             // [32][1032]
    f16* Wc_lds = smem + 32 * 1032; // [16][1032]

    int bid = blockIdx.x, tid = threadIdx.x;
    int dir = bid >> 6, lb = bid & 63;
    int gcb = lb * 32;   // gate col base (0..2047)
    int ccb = lb * 16;   // cand col base (0..1023)

    const f16*  proj = dir ? proj_bw : proj_fw;
    const float* Wgh = dir ? Wgh_bw : Wgh_fw;
    const float* Wch = dir ? Wch_bw : Wch_fw;
    const float* h0  = dir ? h0_bw  : h0_fw;
    f16*   h16d  = h16  + dir * (NB * NU);
    f16*   rh16d = rh16 + dir * (NB * NU);
    float* u32d  = u32  + dir * (NB * NU);
    unsigned* flagd = cnt + dir * 1024;   // 64 flags x 16 u32 stride (64B)

    int w = tid >> 6, l = tid & 63;
    int lc = l & 15, lr = (l >> 4) * 4, kq = (l >> 4) * 8;
    int wm = w & 1, wn = w >> 1, wb = w & 1;

    // ---- Wc slice into LDS (proven) ----
    {
        int j2 = tid & 15;
        for (int k = tid >> 4; k < NU; k += 16)
            Wc_lds[j2 * 1032 + k] = (f16)Wch[(size_t)k * 1024 + ccb + j2];
    }

    // ---- Wg fragments -> registers (proven) ----
    f16x8 wgf[32];
    {
        int col = gcb + wn * 16 + lc;
        #pragma unroll
        for (int kt = 0; kt < 32; ++kt) {
            f16x8 t;
            #pragma unroll
            for (int e = 0; e < 8; ++e)
                t[e] = (f16)Wgh[(size_t)(kt * 32 + kq + e) * 2048 + col];
            wgf[kt] = t;
        }
    }

    // ---- init h: publish h16 (disjoint slices); cand h in regs ----
    {
        int base = lb * 512;
        for (int i = tid; i < 512; i += 256)
            cstore16(h16d + base + i, (f16)h0[base + i]);
    }
    f32x4 hreg = {};
    if (w < 2) {
        #pragma unroll
        for (int q = 0; q < 4; ++q)
            hreg[q] = h0[(size_t)(wb * 16 + lr + q) * NU + ccb + lc];
    }

    int gc  = gcb + wn * 16 + lc;
    int cc  = ccb + lc;
    int cc2 = 2048 + ccb + lc;

    // ---- prefetch step-0 proj operands (constant data; arbitrarily early) ----
    f16 pg[4], pc[4];
    {
        int td0 = dir ? (NT - 1) : 0;
        const f16* pr = proj + (size_t)td0 * NB * 3072;
        #pragma unroll
        for (int q = 0; q < 4; ++q) {
            pg[q] = pr[(size_t)(wm * 16 + lr + q) * 3072 + gc];
            pc[q] = pr[(size_t)(wb * 16 + lr + q) * 3072 + cc2];
        }
    }

    unsigned bc = 1;
    gbar(flagd, lb, bc);

    for (int tl = 0; tl < NT; ++tl) {
        int td = dir ? (NT - 1 - tl) : tl;

        // ---- stage h16 -> LDS ----
        stage32(h16d, stg, tid);
        asm volatile("s_waitcnt lgkmcnt(0)" ::: "memory");
        __builtin_amdgcn_sched_barrier(0);
        barsync();

        // ---- phase A: ru = sigmoid(proj_g + h @ Wg_h) ----
        {
            const f16* ap = &stg[(wm * 16 + lc) * 1032 + kq];
            f32x4 acc0 = {}, acc1 = {};
            #pragma unroll
            for (int kt = 0; kt < 32; kt += 2) {
                f16x8 a0 = *(const f16x8*)(ap + kt * 32);
                f16x8 a1 = *(const f16x8*)(ap + (kt + 1) * 32);
                acc0 = __builtin_amdgcn_mfma_f32_16x16x32_f16(a0, wgf[kt], acc0, 0, 0, 0);
                acc1 = __builtin_amdgcn_mfma_f32_16x16x32_f16(a1, wgf[kt + 1], acc1, 0, 0, 0);
            }
            f32x4 acc = acc0 + acc1;
            #pragma unroll
            for (int q = 0; q < 4; ++q) {
                int br = wm * 16 + lr + q;
                float pre = acc[q] + (float)pg[q];
                float sg = 1.f / (1.f + __expf(-pre));
                if (gc < NU) {   // r-block (block-uniform): rh from staged h16
                    float hv = (float)stg[br * 1032 + gc];
                    cstore16(rh16d + br * NU + gc, (f16)(sg * hv));
                } else {         // u-block
                    cstoref(u32d + br * NU + gc - NU, sg);
                }
            }
        }
        ++bc;
        gbar(flagd, lb, bc);   // barrier #1: rh/u published

        // ---- early u loads (overlap with rh stage) ----
        float uu[4];
        if (w < 2) {
            #pragma unroll
            for (int q = 0; q < 4; ++q)
                uu[q] = cloadf(u32d + (wb * 16 + lr + q) * NU + cc);
        }

        // ---- stage rh16 -> LDS ----
        stage32(rh16d, stg, tid);
        asm volatile("s_waitcnt lgkmcnt(0)" ::: "memory");
        __builtin_amdgcn_sched_barrier(0);
        barsync();

        // ---- phase B: c = tanh(proj_c + (r*h) @ Wc_h); h = u*h + (1-u)*c ----
        if (w < 2) {
            const f16* ap = &stg[(wb * 16 + lc) * 1032 + kq];
            const f16* bptr = Wc_lds + lc * 1032 + kq;
            f32x4 acc0 = {}, acc1 = {};
            #pragma unroll
            for (int kt = 0; kt < 32; kt += 2) {
                f16x8 a0 = *(const f16x8*)(ap + kt * 32);
                f16x8 a1 = *(const f16x8*)(ap + (kt + 1) * 32);
                f16x8 b0 = *(const f16x8*)(bptr + kt * 32);
                f16x8 b1 = *(const f16x8*)(bptr + kt * 32 + 32);
                acc0 = __builtin_amdgcn_mfma_f32_16x16x32_f16(a0, b0, acc0, 0, 0, 0);
                acc1 = __builtin_amdgcn_mfma_f32_16x16x32_f16(a1, b1, acc1, 0, 0, 0);
            }
            f32x4 acc = acc0 + acc1;
            #pragma unroll
            for (int q = 0; q < 4; ++q) {
                int br = wb * 16 + lr + q;
                float pre = acc[q] + (float)pc[q];
                float e2 = __expf(2.f * pre);
                float c = 1.f - 2.f / (e2 + 1.f);   // tanh(pre)
                float hn = uu[q] * hreg[q] + (1.f - uu[q]) * c;
                hreg[q] = hn;
                cstore16(h16d + br * NU + cc, (f16)hn);
            }
        }
        ++bc;
        // barrier #2 inline: drain h16, arrive, then window work, then wait
        asm volatile("s_waitcnt vmcnt(0)" ::: "memory");
        barsync();
        if (tid == 0)
            __hip_atomic_store(&flagd[lb * 16], bc, __ATOMIC_RELAXED,
                               __HIP_MEMORY_SCOPE_AGENT);
        // window: y / final-state stores (not needed by other blocks)
        if (w < 2) {
            #pragma unroll
            for (int q = 0; q < 4; ++q) {
                int br = wb * 16 + lr + q;
                y[(size_t)(td * NB + br) * 2048 + dir * NU + cc] = (f16)hreg[q];
                if (tl == NT - 1)
                    (dir ? st_bw : st_fw)[br * NU + cc] = hreg[q];
            }
        }
        // window: prefetch next step's proj operands (constant data)
        if (tl + 1 < NT) {
            int tdn = dir ? (NT - 2 - tl) : (tl + 1);
            const f16* pr = proj + (size_t)tdn * NB * 3072;
            #pragma unroll
            for (int q = 0; q < 4; ++q) {
                pg[q] = pr[(size_t)(wm * 16 + lr + q) * 3072 + gc];
                pc[q] = pr[(size_t)(wb * 16 + lr + q) * 3072 + cc2];
            }
        }
        gwait(flagd, bc);
        barsync();
    }
}

// ---------------- host launch ----------------
extern "C" void kernel_launch(void* const* d_in, const int* in_sizes, int n_in,
                              void* d_out, int out_size, void* d_ws, size_t ws_size,
                              hipStream_t stream) {
    const int*   x   = (const int*)  d_in[0];
    const float* emb = (const float*)d_in[1];
    const float* fcW = (const float*)d_in[2];
    const float* fcb = (const float*)d_in[3];
    float* out = (float*)d_out;

    char* ws = (char*)d_ws;
    size_t off = 0;
    f16* seq0   = (f16*)(ws + off); off += (size_t)8192 * 256 * 2;
    f16* ybuf0  = (f16*)(ws + off); off += (size_t)8192 * 2048 * 2;
    f16* ybuf1  = (f16*)(ws + off); off += (size_t)8192 * 2048 * 2;
    f16* projfw = (f16*)(ws + off); off += (size_t)8192 * 3072 * 2;
    f16* projbw = (f16*)(ws + off); off += (size_t)8192 * 3072 * 2;
    f16*   h16  = (f16*)(ws + off);   off += 2 * 32 * 1024 * 2;
    f16*   rh16 = (f16*)(ws + off);   off += 2 * 32 * 1024 * 2;
    float* u32  = (float*)(ws + off); off += 2 * 32 * 1024 * 4;
    unsigned* ctrl = (unsigned*)(ws + off); off += 3 * 8192;   // 3 layers x 2048 u32
    // per-layer-reused f16 transposed-weight slot (max-layer sizes, K2=3072)
    f16* WgT_fw = (f16*)(ws + off); off += (size_t)2048 * 3072 * 2;
    f16* WgT_bw = (f16*)(ws + off); off += (size_t)2048 * 3072 * 2;
    f16* WcT_fw = (f16*)(ws + off); off += (size_t)1024 * 3072 * 2;
    f16* WcT_bw = (f16*)(ws + off); off += (size_t)1024 * 3072 * 2;
    bool cvt = (ws_size >= off);   // fall back to f32 gemm if slot doesn't fit

    hipFuncSetAttribute((const void*)gru_layer,
                        hipFuncAttributeMaxDynamicSharedMemorySize, 99072);

    hipMemsetAsync(ctrl, 0, 3 * 8192, stream);
    embed_kernel<<<dim3(8192), dim3(256), 0, stream>>>(x, emb, seq0);

    const f16* lin = seq0; int lda = 256, K = 256;
    f16* ybufs[2] = {ybuf0, ybuf1};
    for (int l = 0; l < 3; ++l) {
        const float* Wg_fw = (const float*)d_in[4 + l * 10 + 0];
        const float* bg_fw = (const float*)d_in[4 + l * 10 + 1];
        const float* Wc_fw = (const float*)d_in[4 + l * 10 + 2];
        const float* bc_fw = (const float*)d_in[4 + l * 10 + 3];
        const float* h0_fw = (const float*)d_in[4 + l * 10 + 4];
        const float* Wg_bw = (const float*)d_in[4 + l * 10 + 5];
        const float* bg_bw = (const float*)d_in[4 + l * 10 + 6];
        const float* Wc_bw = (const float*)d_in[4 + l * 10 + 7];
        const float* bc_bw = (const float*)d_in[4 + l * 10 + 8];
        const float* h0_bw = (const float*)d_in[4 + l * 10 + 9];
        int din = (l == 0) ? 256 : 2048;
        int K2 = din + 1024;

        if (cvt) {
            wconv<<<dim3(K2 / 32, 64, 2), dim3(256), 0, stream>>>(Wg_fw, Wc_fw, WgT_fw, WcT_fw, K2);
            wconv<<<dim3(K2 / 32, 64, 2), dim3(256), 0, stream>>>(Wg_bw, Wc_bw, WgT_bw, WcT_bw, K2);
            gemm_projT<<<dim3(64, 24), dim3(256), 0, stream>>>(lin, lda, K, WgT_fw, WcT_fw, K2, bg_fw, bc_fw, projfw);
            gemm_projT<<<dim3(64, 24), dim3(256), 0, stream>>>(lin, lda, K, WgT_bw, WcT_bw, K2, bg_bw, bc_bw, projbw);
        } else {
            gemm_proj<<<dim3(64, 24), dim3(256), 0, stream>>>(lin, lda, K, Wg_fw, Wc_fw, bg_fw, bc_fw, projfw);
            gemm_proj<<<dim3(64, 24), dim3(256), 0, stream>>>(lin, lda, K, Wg_bw, Wc_bw, bg_bw, bc_bw, projbw);
        }

        const float* Wgh_fw = Wg_fw + (size_t)din * 2048;
        const float* Wgh_bw = Wg_bw + (size_t)din * 2048;
        const float* Wch_fw = Wc_fw + (size_t)din * 1024;
        const float* Wch_bw = Wc_bw + (size_t)din * 1024;
        f16* yout = ybufs[l & 1];
        float* stfw = out + 1048576 + l * 32768;
        float* stbw = out + 1048576 + 98304 + l * 32768;
        unsigned* cnt = ctrl + l * 2048;

        gru_layer<<<dim3(128), dim3(256), 99072, stream>>>(
            projfw, projbw, Wgh_fw, Wgh_bw, Wch_fw, Wch_bw, h0_fw, h0_bw,
            h16, rh16, u32, yout, stfw, stbw, cnt);
        lin = yout; lda = 2048; K = 2048;
    }

    gemm_fc<<<dim3(64), dim3(256), 0, stream>>>(ybufs[0], fcW, fcb, out);
}

// Round 10
// 5764.718 us; speedup vs baseline: 6.0607x; 1.1211x over previous
//
#include <hip/hip_runtime.h>

typedef _Float16 f16;
typedef _Float16 f16x4 __attribute__((ext_vector_type(4)));
typedef _Float16 f16x8 __attribute__((ext_vector_type(8)));
typedef float f32x4 __attribute__((ext_vector_type(4)));

#define NB 32
#define NT 256
#define NE 256
#define NU 1024
#define NV 128

#define MEMF() asm volatile("" ::: "memory")

// ---------- agent-coherent (cross-XCD, L3-level) load/store helpers ----------
__device__ __forceinline__ unsigned long long cload64(const f16* p) {
    return __hip_atomic_load((const unsigned long long*)p, __ATOMIC_RELAXED,
                             __HIP_MEMORY_SCOPE_AGENT);
}
__device__ __forceinline__ float cloadf(const float* p) {
    return __hip_atomic_load(p, __ATOMIC_RELAXED, __HIP_MEMORY_SCOPE_AGENT);
}
__device__ __forceinline__ void cstoref(float* p, float v) {
    __hip_atomic_store(p, v, __ATOMIC_RELAXED, __HIP_MEMORY_SCOPE_AGENT);
}
__device__ __forceinline__ void cstore16(f16* p, f16 v) {
    __hip_atomic_store((unsigned short*)p, __builtin_bit_cast(unsigned short, v),
                       __ATOMIC_RELAXED, __HIP_MEMORY_SCOPE_AGENT);
}

__device__ __forceinline__ void barsync() {
    MEMF();
    __builtin_amdgcn_s_barrier();
    MEMF();
}

// wave-0 vector poll over a 32-block domain: lane l watches flag (l&31).
__device__ __forceinline__ void gwait(const unsigned* flagd, unsigned target) {
    if (threadIdx.x < 64) {
        int it = 0;
        for (;;) {
            unsigned v = __hip_atomic_load(&flagd[(threadIdx.x & 31) * 16],
                                           __ATOMIC_RELAXED, __HIP_MEMORY_SCOPE_AGENT);
            if (__all(v >= target)) break;
            if (++it > (1 << 16)) break;  // failsafe: fail visibly, don't hang
        }
    }
}

// full barrier over the block's 32-member domain
__device__ __forceinline__ void gbar(unsigned* flagd, int cg, unsigned target) {
    asm volatile("s_waitcnt vmcnt(0)" ::: "memory");
    barsync();
    if (threadIdx.x == 0)
        __hip_atomic_store(&flagd[cg * 16], target, __ATOMIC_RELAXED,
                           __HIP_MEMORY_SCOPE_AGENT);
    gwait(flagd, target);
    barsync();
}

// stage 16 rows x 1024 f16 from agent-coherent global into LDS (pitch 1032).
// All 16 loads issued before any LDS write -> one L3 round trip.
__device__ __forceinline__ void stage16(const f16* __restrict__ src,
                                        f16* __restrict__ stg, int tid) {
    unsigned long long a[16];
    #pragma unroll
    for (int i = 0; i < 16; ++i)
        a[i] = cload64(src + i * NU + tid * 4);
    MEMF();
    #pragma unroll
    for (int i = 0; i < 16; ++i)
        *(f16x4*)(&stg[i * 1032 + tid * 4]) = __builtin_bit_cast(f16x4, a[i]);
}

// ---------------- embedding ----------------
__global__ void embed_kernel(const int* __restrict__ x, const float* __restrict__ emb,
                             f16* __restrict__ seq0) {
    int row = blockIdx.x;           // t*NB + b
    int t = row >> 5, b = row & 31;
    int e = threadIdx.x;
    int idx = x[b * NT + t];
    seq0[row * NE + e] = (f16)emb[idx * NE + e];
}

// ---------------- weight transpose+convert: WT[n][k] (f16) = W[k][n] (f32) ----------------
__global__ void wconv(const float* __restrict__ Wg, const float* __restrict__ Wc,
                      f16* __restrict__ WgT, f16* __restrict__ WcT, int K2) {
    __shared__ float tile[32][33];
    int mat = blockIdx.z & 1;
    const float* in = mat ? Wc : Wg;
    f16* outp = mat ? WcT : WgT;
    int N = mat ? 1024 : 2048;
    int by = blockIdx.y;
    if (by * 32 >= N) return;
    int k0 = blockIdx.x * 32, n0 = by * 32;
    int tx = threadIdx.x & 31, ty = threadIdx.x >> 5;  // 32 x 8
    #pragma unroll
    for (int i = 0; i < 4; ++i) {
        int r = ty * 4 + i;
        tile[r][tx] = in[(size_t)(k0 + r) * N + n0 + tx];
    }
    __syncthreads();
    #pragma unroll
    for (int i = 0; i < 4; ++i) {
        int rn = ty * 4 + i;
        outp[(size_t)(n0 + rn) * K2 + k0 + tx] = (f16)tile[tx][rn];
    }
}

// ---------------- input-projection GEMM, f16 transposed-weight edition ----------------
__launch_bounds__(256)
__global__ void gemm_projT(const f16* __restrict__ A, int lda, int K,
                           const f16* __restrict__ WgT, const f16* __restrict__ WcT, int K2,
                           const float* __restrict__ bg, const float* __restrict__ bc,
                           f16* __restrict__ proj) {
    __shared__ f16 As[128][40];
    __shared__ f16 Bs[128][40];
    int cb = blockIdx.y;
    const f16* Bsrc; int outcol; const float* bias;
    if (cb < 16) { Bsrc = WgT + (size_t)cb * 128 * K2; outcol = cb * 128; bias = bg + cb * 128; }
    else { Bsrc = WcT + (size_t)(cb - 16) * 128 * K2; outcol = 2048 + (cb - 16) * 128; bias = bc + (cb - 16) * 128; }
    int m0 = blockIdx.x * 128;
    int tid = threadIdx.x;
    int w = tid >> 6, l = tid & 63;
    int wm = w & 1, wn = w >> 1;
    f32x4 acc[4][4] = {};
    for (int k0 = 0; k0 < K; k0 += 32) {
        __syncthreads();
        #pragma unroll
        for (int p = 0; p < 2; ++p) {
            int e = (p * 256 + tid) * 8;
            int r = e >> 5, kq = e & 31;
            f16x8 v = *(const f16x8*)(A + (size_t)(m0 + r) * lda + k0 + kq);
            *(f16x8*)(&As[r][kq]) = v;
        }
        #pragma unroll
        for (int p = 0; p < 2; ++p) {
            int e = (p * 256 + tid) * 8;
            int r = e >> 5, kq = e & 31;
            f16x8 v = *(const f16x8*)(Bsrc + (size_t)r * K2 + k0 + kq);
            *(f16x8*)(&Bs[r][kq]) = v;
        }
        __syncthreads();
        int kq = (l >> 4) * 8;
        f16x8 a[4], b[4];
        #pragma unroll
        for (int i = 0; i < 4; ++i) a[i] = *(const f16x8*)(&As[wm * 64 + i * 16 + (l & 15)][kq]);
        #pragma unroll
        for (int j = 0; j < 4; ++j) b[j] = *(const f16x8*)(&Bs[wn * 64 + j * 16 + (l & 15)][kq]);
        #pragma unroll
        for (int i = 0; i < 4; ++i)
            #pragma unroll
            for (int j = 0; j < 4; ++j)
                acc[i][j] = __builtin_amdgcn_mfma_f32_16x16x32_f16(a[i], b[j], acc[i][j], 0, 0, 0);
    }
    int lr = (l >> 4) * 4, lc = l & 15;
    #pragma unroll
    for (int i = 0; i < 4; ++i) {
        #pragma unroll
        for (int j = 0; j < 4; ++j) {
            int gcol = wn * 64 + j * 16 + lc;
            float bia = bias[gcol];
            #pragma unroll
            for (int q = 0; q < 4; ++q) {
                int grow = m0 + wm * 64 + i * 16 + lr + q;
                proj[(size_t)grow * 3072 + outcol + gcol] = (f16)(acc[i][j][q] + bia);
            }
        }
    }
}

// ---------------- input-projection GEMM (fallback, f32 weights) ----------------
__launch_bounds__(256)
__global__ void gemm_proj(const f16* __restrict__ A, int lda, int K,
                          const float* __restrict__ Wg, const float* __restrict__ Wc,
                          const float* __restrict__ bg, const float* __restrict__ bc,
                          f16* __restrict__ proj) {
    __shared__ f16 As[128][40];
    __shared__ f16 Bs[128][40];
    int cb = blockIdx.y;
    const float* Bsrc; int ldb, outcol; const float* bias;
    if (cb < 16) { Bsrc = Wg + cb * 128; ldb = 2 * NU; outcol = cb * 128; bias = bg + cb * 128; }
    else { Bsrc = Wc + (cb - 16) * 128; ldb = NU; outcol = 2 * NU + (cb - 16) * 128; bias = bc + (cb - 16) * 128; }
    int m0 = blockIdx.x * 128;
    int tid = threadIdx.x;
    int w = tid >> 6, l = tid & 63;
    int wm = w & 1, wn = w >> 1;
    f32x4 acc[4][4] = {};
    for (int k0 = 0; k0 < K; k0 += 32) {
        __syncthreads();
        #pragma unroll
        for (int p = 0; p < 2; ++p) {
            int e = (p * 256 + tid) * 8;
            int r = e >> 5, kq = e & 31;
            f16x8 v = *(const f16x8*)(A + (size_t)(m0 + r) * lda + k0 + kq);
            *(f16x8*)(&As[r][kq]) = v;
        }
        #pragma unroll
        for (int p = 0; p < 4; ++p) {
            int k = p * 8 + (tid >> 5);
            int n = (tid & 31) * 4;
            float4 v = *(const float4*)(Bsrc + (size_t)(k0 + k) * ldb + n);
            Bs[n + 0][k] = (f16)v.x; Bs[n + 1][k] = (f16)v.y;
            Bs[n + 2][k] = (f16)v.z; Bs[n + 3][k] = (f16)v.w;
        }
        __syncthreads();
        int kq = (l >> 4) * 8;
        f16x8 a[4], b[4];
        #pragma unroll
        for (int i = 0; i < 4; ++i) a[i] = *(const f16x8*)(&As[wm * 64 + i * 16 + (l & 15)][kq]);
        #pragma unroll
        for (int j = 0; j < 4; ++j) b[j] = *(const f16x8*)(&Bs[wn * 64 + j * 16 + (l & 15)][kq]);
        #pragma unroll
        for (int i = 0; i < 4; ++i)
            #pragma unroll
            for (int j = 0; j < 4; ++j)
                acc[i][j] = __builtin_amdgcn_mfma_f32_16x16x32_f16(a[i], b[j], acc[i][j], 0, 0, 0);
    }
    int lr = (l >> 4) * 4, lc = l & 15;
    #pragma unroll
    for (int i = 0; i < 4; ++i) {
        #pragma unroll
        for (int j = 0; j < 4; ++j) {
            int gcol = wn * 64 + j * 16 + lc;
            float bia = bias[gcol];
            #pragma unroll
            for (int q = 0; q < 4; ++q) {
                int grow = m0 + wm * 64 + i * 16 + lr + q;
                proj[(size_t)grow * 3072 + outcol + gcol] = (f16)(acc[i][j][q] + bia);
            }
        }
    }
}

// ---------------- final FC ----------------
__launch_bounds__(256)
__global__ void gemm_fc(const f16* __restrict__ y, const float* __restrict__ W,
                        const float* __restrict__ bias, float* __restrict__ out) {
    __shared__ f16 As[128][40];
    __shared__ f16 Bs[128][40];
    int m0 = blockIdx.x * 128;
    int tid = threadIdx.x;
    int w = tid >> 6, l = tid & 63;
    int wm = w & 1, wn = w >> 1;
    f32x4 acc[4][4] = {};
    for (int k0 = 0; k0 < 2048; k0 += 32) {
        __syncthreads();
        #pragma unroll
        for (int p = 0; p < 2; ++p) {
            int e = (p * 256 + tid) * 8;
            int r = e >> 5, kq = e & 31;
            int grow = m0 + r;                 // row = b*256 + t
            int b = grow >> 8, t = grow & 255;
            f16x8 v = *(const f16x8*)(y + (size_t)(t * 32 + b) * 2048 + k0 + kq);
            *(f16x8*)(&As[r][kq]) = v;
        }
        #pragma unroll
        for (int p = 0; p < 4; ++p) {
            int k = p * 8 + (tid >> 5);
            int n = (tid & 31) * 4;
            float4 v = *(const float4*)(W + (size_t)(k0 + k) * 128 + n);
            Bs[n + 0][k] = (f16)v.x; Bs[n + 1][k] = (f16)v.y;
            Bs[n + 2][k] = (f16)v.z; Bs[n + 3][k] = (f16)v.w;
        }
        __syncthreads();
        int kq = (l >> 4) * 8;
        f16x8 a[4], b[4];
        #pragma unroll
        for (int i = 0; i < 4; ++i) a[i] = *(const f16x8*)(&As[wm * 64 + i * 16 + (l & 15)][kq]);
        #pragma unroll
        for (int j = 0; j < 4; ++j) b[j] = *(const f16x8*)(&Bs[wn * 64 + j * 16 + (l & 15)][kq]);
        #pragma unroll
        for (int i = 0; i < 4; ++i)
            #pragma unroll
            for (int j = 0; j < 4; ++j)
                acc[i][j] = __builtin_amdgcn_mfma_f32_16x16x32_f16(a[i], b[j], acc[i][j], 0, 0, 0);
    }
    int lr = (l >> 4) * 4, lc = l & 15;
    #pragma unroll
    for (int i = 0; i < 4; ++i) {
        #pragma unroll
        for (int j = 0; j < 4; ++j) {
            int gcol = wn * 64 + j * 16 + lc;
            float bia = bias[gcol];
            #pragma unroll
            for (int q = 0; q < 4; ++q) {
                int grow = m0 + wm * 64 + i * 16 + lr + q;
                out[(size_t)grow * 128 + gcol] = acc[i][j][q] + bia;
            }
        }
    }
}

// ---------------- recurrent bidirectional GRU layer ----------------
// Row-split edition: 128 blocks x 256 threads. Block = (dir, rowhalf rh_i, colgroup cg).
// Each (dir,rowhalf) is an INDEPENDENT 16-row chain with its own 32-block barrier
// domain (batch rows don't couple in a GRU). Per block: 64 gate cols (4 waves,
// wgf[32] in regs) + 32 cand cols (waves 0-1, Wc in LDS). LDS: stage[16][1032]
// (33KB) + Wc[32][1032] (66KB) = 99072B (proven size). Normal launch.
__launch_bounds__(256)
__global__ void gru_layer(
    const f16* __restrict__ proj_fw, const f16* __restrict__ proj_bw,
    const float* __restrict__ Wgh_fw, const float* __restrict__ Wgh_bw,
    const float* __restrict__ Wch_fw, const float* __restrict__ Wch_bw,
    const float* __restrict__ h0_fw, const float* __restrict__ h0_bw,
    f16* __restrict__ h16, f16* __restrict__ rh16, float* __restrict__ u32,
    f16* __restrict__ y, float* __restrict__ st_fw, float* __restrict__ st_bw,
    unsigned* __restrict__ cnt)
{
    extern __shared__ f16 smem[];
    f16* stg    = smem;             // [16][1032]
    f16* Wc_lds = smem + 16 * 1032; // [32][1032]

    int bid = blockIdx.x, tid = threadIdx.x;
    int dir = bid >> 6, lb = bid & 63;
    int rh_i = lb >> 5;          // row half (rows R0..R0+15)
    int cg   = lb & 31;          // col group
    int R0   = rh_i * 16;
    int gcb  = cg * 64;          // gate col base (0..1983)
    int ccb  = cg * 32;          // cand col base (0..991)

    const f16*  proj = dir ? proj_bw : proj_fw;
    const float* Wgh = dir ? Wgh_bw : Wgh_fw;
    const float* Wch = dir ? Wch_bw : Wch_fw;
    const float* h0  = dir ? h0_bw  : h0_fw;
    f16*   h16d  = h16  + dir * (NB * NU);
    f16*   rh16d = rh16 + dir * (NB * NU);
    float* u32d  = u32  + dir * (NB * NU);
    unsigned* flagd = cnt + (dir * 2 + rh_i) * 1024;  // 32 flags x 64B stride

    const f16* hsrc  = h16d  + (size_t)R0 * NU;
    const f16* rhsrc = rh16d + (size_t)R0 * NU;

    int w = tid >> 6, l = tid & 63;
    int lc = l & 15, lr = (l >> 4) * 4, kq = (l >> 4) * 8;

    // ---- Wc slice (32 cols) into LDS ----
    {
        int j2 = tid & 31;
        for (int k = tid >> 5; k < NU; k += 8)
            Wc_lds[j2 * 1032 + k] = (f16)Wch[(size_t)k * 1024 + ccb + j2];
    }

    // ---- Wg fragments -> registers (wave w covers col tile w of 4) ----
    f16x8 wgf[32];
    {
        int col = gcb + w * 16 + lc;
        #pragma unroll
        for (int kt = 0; kt < 32; ++kt) {
            f16x8 t;
            #pragma unroll
            for (int e = 0; e < 8; ++e)
                t[e] = (f16)Wgh[(size_t)(kt * 32 + kq + e) * 2048 + col];
            wgf[kt] = t;
        }
    }

    // ---- init h: publish h16 (disjoint 512-elem slices; domain-local rows) ----
    {
        int base = lb * 512;
        for (int i = tid; i < 512; i += 256)
            cstore16(h16d + base + i, (f16)h0[base + i]);
    }
    // cand h in regs (waves 0-1: col tile w of 2)
    f32x4 hreg = {};
    if (w < 2) {
        #pragma unroll
        for (int q = 0; q < 4; ++q)
            hreg[q] = h0[(size_t)(R0 + lr + q) * NU + ccb + w * 16 + lc];
    }

    int gc  = gcb + w * 16 + lc;           // gate col (this wave)
    int cc  = ccb + (w & 1) * 16 + lc;     // cand col (waves 0-1)
    int cc2 = 2048 + cc;
    bool rblk = (cg < 16);                 // block-uniform

    // ---- prefetch step-0 proj operands ----
    f16 pg[4], pc[4];
    {
        int td0 = dir ? (NT - 1) : 0;
        const f16* pr = proj + (size_t)td0 * NB * 3072;
        #pragma unroll
        for (int q = 0; q < 4; ++q) {
            pg[q] = pr[(size_t)(R0 + lr + q) * 3072 + gc];
            pc[q] = pr[(size_t)(R0 + lr + q) * 3072 + cc2];
        }
    }

    unsigned bc = 1;
    gbar(flagd, cg, bc);

    for (int tl = 0; tl < NT; ++tl) {
        int td = dir ? (NT - 1 - tl) : tl;

        // ---- stage h (16 rows) -> LDS ----
        stage16(hsrc, stg, tid);
        asm volatile("s_waitcnt lgkmcnt(0)" ::: "memory");
        __builtin_amdgcn_sched_barrier(0);
        barsync();

        // ---- phase A: ru = sigmoid(proj_g + h @ Wg_h)  (all 4 waves) ----
        {
            const f16* ap = &stg[lc * 1032 + kq];
            f32x4 acc0 = {}, acc1 = {};
            #pragma unroll
            for (int kt = 0; kt < 32; kt += 2) {
                f16x8 a0 = *(const f16x8*)(ap + kt * 32);
                f16x8 a1 = *(const f16x8*)(ap + (kt + 1) * 32);
                acc0 = __builtin_amdgcn_mfma_f32_16x16x32_f16(a0, wgf[kt], acc0, 0, 0, 0);
                acc1 = __builtin_amdgcn_mfma_f32_16x16x32_f16(a1, wgf[kt + 1], acc1, 0, 0, 0);
            }
            f32x4 acc = acc0 + acc1;
            #pragma unroll
            for (int q = 0; q < 4; ++q) {
                int br = lr + q;           // local row
                float pre = acc[q] + (float)pg[q];
                float sg = 1.f / (1.f + __expf(-pre));
                if (rblk) {   // r-block: rh from staged h
                    float hv = (float)stg[br * 1032 + gc];
                    cstore16(rh16d + (size_t)(R0 + br) * NU + gc, (f16)(sg * hv));
                } else {      // u-block
                    cstoref(u32d + (size_t)(R0 + br) * NU + gc - NU, sg);
                }
            }
        }
        ++bc;
        gbar(flagd, cg, bc);   // barrier #1: rh/u published

        // ---- early u loads (overlap with rh stage) ----
        float uu[4];
        if (w < 2) {
            #pragma unroll
            for (int q = 0; q < 4; ++q)
                uu[q] = cloadf(u32d + (size_t)(R0 + lr + q) * NU + cc);
        }

        // ---- stage rh (16 rows) -> LDS ----
        stage16(rhsrc, stg, tid);
        asm volatile("s_waitcnt lgkmcnt(0)" ::: "memory");
        __builtin_amdgcn_sched_barrier(0);
        barsync();

        // ---- phase B: c = tanh(proj_c + (r*h) @ Wc_h); h = u*h + (1-u)*c ----
        if (w < 2) {
            const f16* ap = &stg[lc * 1032 + kq];
            const f16* bptr = Wc_lds + ((w & 1) * 16 + lc) * 1032 + kq;
            f32x4 acc0 = {}, acc1 = {};
            #pragma unroll
            for (int kt = 0; kt < 32; kt += 2) {
                f16x8 a0 = *(const f16x8*)(ap + kt * 32);
                f16x8 a1 = *(const f16x8*)(ap + (kt + 1) * 32);
                f16x8 b0 = *(const f16x8*)(bptr + kt * 32);
                f16x8 b1 = *(const f16x8*)(bptr + kt * 32 + 32);
                acc0 = __builtin_amdgcn_mfma_f32_16x16x32_f16(a0, b0, acc0, 0, 0, 0);
                acc1 = __builtin_amdgcn_mfma_f32_16x16x32_f16(a1, b1, acc1, 0, 0, 0);
            }
            f32x4 acc = acc0 + acc1;
            #pragma unroll
            for (int q = 0; q < 4; ++q) {
                int br = R0 + lr + q;      // global row
                float pre = acc[q] + (float)pc[q];
                float e2 = __expf(2.f * pre);
                float c = 1.f - 2.f / (e2 + 1.f);   // tanh(pre)
                float hn = uu[q] * hreg[q] + (1.f - uu[q]) * c;
                hreg[q] = hn;
                cstore16(h16d + (size_t)br * NU + cc, (f16)hn);
            }
        }
        ++bc;
        // barrier #2 inline: drain h16, arrive, then window work, then wait
        asm volatile("s_waitcnt vmcnt(0)" ::: "memory");
        barsync();
        if (tid == 0)
            __hip_atomic_store(&flagd[cg * 16], bc, __ATOMIC_RELAXED,
                               __HIP_MEMORY_SCOPE_AGENT);
        // window: y / final-state stores (not needed by other blocks)
        if (w < 2) {
            #pragma unroll
            for (int q = 0; q < 4; ++q) {
                int br = R0 + lr + q;
                y[(size_t)(td * NB + br) * 2048 + dir * NU + cc] = (f16)hreg[q];
                if (tl == NT - 1)
                    (dir ? st_bw : st_fw)[(size_t)br * NU + cc] = hreg[q];
            }
        }
        // window: prefetch next step's proj operands
        if (tl + 1 < NT) {
            int tdn = dir ? (NT - 2 - tl) : (tl + 1);
            const f16* pr = proj + (size_t)tdn * NB * 3072;
            #pragma unroll
            for (int q = 0; q < 4; ++q) {
                pg[q] = pr[(size_t)(R0 + lr + q) * 3072 + gc];
                pc[q] = pr[(size_t)(R0 + lr + q) * 3072 + cc2];
            }
        }
        gwait(flagd, bc);
        barsync();
    }
}

// ---------------- host launch ----------------
extern "C" void kernel_launch(void* const* d_in, const int* in_sizes, int n_in,
                              void* d_out, int out_size, void* d_ws, size_t ws_size,
                              hipStream_t stream) {
    const int*   x   = (const int*)  d_in[0];
    const float* emb = (const float*)d_in[1];
    const float* fcW = (const float*)d_in[2];
    const float* fcb = (const float*)d_in[3];
    float* out = (float*)d_out;

    char* ws = (char*)d_ws;
    size_t off = 0;
    f16* seq0   = (f16*)(ws + off); off += (size_t)8192 * 256 * 2;
    f16* ybuf0  = (f16*)(ws + off); off += (size_t)8192 * 2048 * 2;
    f16* ybuf1  = (f16*)(ws + off); off += (size_t)8192 * 2048 * 2;
    f16* projfw = (f16*)(ws + off); off += (size_t)8192 * 3072 * 2;
    f16* projbw = (f16*)(ws + off); off += (size_t)8192 * 3072 * 2;
    f16*   h16  = (f16*)(ws + off);   off += 2 * 32 * 1024 * 2;
    f16*   rh16 = (f16*)(ws + off);   off += 2 * 32 * 1024 * 2;
    float* u32  = (float*)(ws + off); off += 2 * 32 * 1024 * 4;
    unsigned* ctrl = (unsigned*)(ws + off); off += 3 * 16384;  // 3 layers x 4096 u32
    // per-layer-reused f16 transposed-weight slot (max-layer sizes, K2=3072)
    f16* WgT_fw = (f16*)(ws + off); off += (size_t)2048 * 3072 * 2;
    f16* WgT_bw = (f16*)(ws + off); off += (size_t)2048 * 3072 * 2;
    f16* WcT_fw = (f16*)(ws + off); off += (size_t)1024 * 3072 * 2;
    f16* WcT_bw = (f16*)(ws + off); off += (size_t)1024 * 3072 * 2;
    bool cvt = (ws_size >= off);   // fall back to f32 gemm if slot doesn't fit

    hipFuncSetAttribute((const void*)gru_layer,
                        hipFuncAttributeMaxDynamicSharedMemorySize, 99072);

    hipMemsetAsync(ctrl, 0, 3 * 16384, stream);
    embed_kernel<<<dim3(8192), dim3(256), 0, stream>>>(x, emb, seq0);

    const f16* lin = seq0; int lda = 256, K = 256;
    f16* ybufs[2] = {ybuf0, ybuf1};
    for (int l = 0; l < 3; ++l) {
        const float* Wg_fw = (const float*)d_in[4 + l * 10 + 0];
        const float* bg_fw = (const float*)d_in[4 + l * 10 + 1];
        const float* Wc_fw = (const float*)d_in[4 + l * 10 + 2];
        const float* bc_fw = (const float*)d_in[4 + l * 10 + 3];
        const float* h0_fw = (const float*)d_in[4 + l * 10 + 4];
        const float* Wg_bw = (const float*)d_in[4 + l * 10 + 5];
        const float* bg_bw = (const float*)d_in[4 + l * 10 + 6];
        const float* Wc_bw = (const float*)d_in[4 + l * 10 + 7];
        const float* bc_bw = (const float*)d_in[4 + l * 10 + 8];
        const float* h0_bw = (const float*)d_in[4 + l * 10 + 9];
        int din = (l == 0) ? 256 : 2048;
        int K2 = din + 1024;

        if (cvt) {
            wconv<<<dim3(K2 / 32, 64, 2), dim3(256), 0, stream>>>(Wg_fw, Wc_fw, WgT_fw, WcT_fw, K2);
            wconv<<<dim3(K2 / 32, 64, 2), dim3(256), 0, stream>>>(Wg_bw, Wc_bw, WgT_bw, WcT_bw, K2);
            gemm_projT<<<dim3(64, 24), dim3(256), 0, stream>>>(lin, lda, K, WgT_fw, WcT_fw, K2, bg_fw, bc_fw, projfw);
            gemm_projT<<<dim3(64, 24), dim3(256), 0, stream>>>(lin, lda, K, WgT_bw, WcT_bw, K2, bg_bw, bc_bw, projbw);
        } else {
            gemm_proj<<<dim3(64, 24), dim3(256), 0, stream>>>(lin, lda, K, Wg_fw, Wc_fw, bg_fw, bc_fw, projfw);
            gemm_proj<<<dim3(64, 24), dim3(256), 0, stream>>>(lin, lda, K, Wg_bw, Wc_bw, bg_bw, bc_bw, projbw);
        }

        const float* Wgh_fw = Wg_fw + (size_t)din * 2048;
        const float* Wgh_bw = Wg_bw + (size_t)din * 2048;
        const float* Wch_fw = Wc_fw + (size_t)din * 1024;
        const float* Wch_bw = Wc_bw + (size_t)din * 1024;
        f16* yout = ybufs[l & 1];
        float* stfw = out + 1048576 + l * 32768;
        float* stbw = out + 1048576 + 98304 + l * 32768;
        unsigned* cnt = ctrl + l * 4096;

        gru_layer<<<dim3(128), dim3(256), 99072, stream>>>(
            projfw, projbw, Wgh_fw, Wgh_bw, Wch_fw, Wch_bw, h0_fw, h0_bw,
            h16, rh16, u32, yout, stfw, stbw, cnt);
        lin = yout; lda = 2048; K = 2048;
    }

    gemm_fc<<<dim3(64), dim3(256), 0, stream>>>(ybufs[0], fcW, fcb, out);
}